// Round 2
// baseline (1518.304 us; speedup 1.0000x reference)
//
#include <hip/hip_runtime.h>
#include <stdint.h>

#define M_TOK   8192
#define DMODEL  1024
#define DDICT   16384
#define TOPK    32
#define MAXC    256     // per-row candidate capacity (E[cnt]~98, P(>256)~0)
#define MAXA    64      // ambiguous-boundary refine capacity (E~13)
#define DELTA   0.03f   // certainty margin vs bf16-GEMM error (sigma ~1e-3)

typedef __attribute__((ext_vector_type(8))) short bf16x8;
typedef __attribute__((ext_vector_type(4))) float f32x4;

// ---------------------------------------------------------------- helpers
__device__ __forceinline__ unsigned short f32_to_bf16(float f) {
  unsigned u = __float_as_uint(f);
  unsigned r = 0x7FFFu + ((u >> 16) & 1u);   // round-to-nearest-even
  return (unsigned short)((u + r) >> 16);
}

#define GLD16(g, l)                                                        \
  __builtin_amdgcn_global_load_lds(                                        \
      (const __attribute__((address_space(1))) void*)(g),                  \
      (__attribute__((address_space(3))) void*)(l), 16, 0, 0)

// ---------------------------------------------------------------- x cast + row norm -> tau
__global__ __launch_bounds__(256) void cast_x_norm_kernel(
    const float* __restrict__ x, unsigned short* __restrict__ xbf,
    float* __restrict__ tau) {
  const int row = blockIdx.x, tid = threadIdx.x;
  const int lane = tid & 63, wave = tid >> 6;
  __shared__ float red[4];
  float4 v = ((const float4*)(x + (size_t)row * DMODEL))[tid];
  ushort4 o;
  o.x = f32_to_bf16(v.x); o.y = f32_to_bf16(v.y);
  o.z = f32_to_bf16(v.z); o.w = f32_to_bf16(v.w);
  ((ushort4*)(xbf + (size_t)row * DMODEL))[tid] = o;
  float ss = v.x * v.x + v.y * v.y + v.z * v.z + v.w * v.w;
#pragma unroll
  for (int off = 32; off; off >>= 1) ss += __shfl_down(ss, off);
  if (lane == 0) red[wave] = ss;
  __syncthreads();
  if (tid == 0) tau[row] = 0.055f * sqrtf(red[0] + red[1] + red[2] + red[3]);
}

// ---------------------------------------------------------------- Wenc cast
__global__ __launch_bounds__(256) void cast_bf16_kernel(
    const float* __restrict__ in, unsigned short* __restrict__ out, int n4) {
  int i = blockIdx.x * 256 + threadIdx.x;
  if (i >= n4) return;
  float4 v = ((const float4*)in)[i];
  ushort4 o;
  o.x = f32_to_bf16(v.x); o.y = f32_to_bf16(v.y);
  o.z = f32_to_bf16(v.z); o.w = f32_to_bf16(v.w);
  ((ushort4*)out)[i] = o;
}

// W_dec [DMODEL, DDICT] -> W_decT [DDICT, DMODEL]
__global__ __launch_bounds__(256) void transpose_kernel(
    const float* __restrict__ in, float* __restrict__ out) {
  __shared__ float tile[32][33];
  int tx = threadIdx.x & 31;
  int ty = threadIdx.x >> 5;
  int c0 = blockIdx.x * 32;
  int r0 = blockIdx.y * 32;
#pragma unroll
  for (int i = 0; i < 32; i += 8)
    tile[ty + i][tx] = in[(size_t)(r0 + ty + i) * DDICT + c0 + tx];
  __syncthreads();
#pragma unroll
  for (int i = 0; i < 32; i += 8)
    out[(size_t)(c0 + ty + i) * DMODEL + r0 + tx] = tile[tx][ty + i];
}

// ---------------------------------------------------------------- encoder GEMM + threshold epilogue
// m97-family structure: 128x128 tile, 4 waves (2Mx2N, wave tile 64x64), BK=32.
// BOTH operands staged coalesced via global_load_lds (16B) into TRIPLE-buffered
// LDS (prefetch distance 2); per K-step the only loop vmem is the 4 staging
// GLD16s, so the end-of-step wait is an exact counted vmcnt(4) -- staging has
// two full steps of latency tolerance, never a vmcnt(0) drain in the loop.
// LDS layout kc-major [kc][row][8] (round-1-verified: GLD16 wave-uniform dest,
// 0 measured bank conflicts on ds_read_b128 fragments).
// XCD-bijective decode (8192 = 8 xcd * 16 cols * 64 rows): each XCD walks bm
// for a fixed bn-column -> its 256KB B panel stays L2-resident.
// Epilogue: fused z-tile zero-fill + |z|>=tau candidate emission (unchanged).
__global__ __launch_bounds__(256, 3) void gemm_enc_kernel(
    const unsigned short* __restrict__ A,
    const unsigned short* __restrict__ B,
    const float* __restrict__ bias,
    const float* __restrict__ tau,
    unsigned* __restrict__ cnt,
    int2* __restrict__ cand,
    float* __restrict__ out_z) {
  __shared__ __align__(16) unsigned short As[3][4][128][8];  // 24 KB
  __shared__ __align__(16) unsigned short Bs[3][4][128][8];  // 24 KB
  __shared__ float taus[128];

  const int tid  = threadIdx.x;
  const int lane = tid & 63;
  const int wave = tid >> 6;
  const int l16  = lane & 15;
  const int quad = lane >> 4;
  const int wm   = (wave >> 1) * 64;   // wave M-half
  const int wn   = (wave & 1) * 64;    // wave N-half

  // XCD-aware bijective decode: lin = xcd + 8*(col*64 + row_i)
  const int lin = blockIdx.x;
  const int xcd = lin & 7;
  const int idx = lin >> 3;            // 0..1023
  const int bn  = (xcd * 16 + (idx >> 6)) * 128;
  const int bm  = (idx & 63) * 128;

  if (tid < 128) taus[tid] = tau[bm + tid];

  // staging: 512 chunks of 16B per operand per K-step, 2 per thread
  const int kc0 = tid >> 7, r0 = tid & 127;   // chunk tid
  const int kc1 = kc0 + 2,  r1 = r0;          // chunk tid+256
  const unsigned short* Ab = A + (size_t)bm * DMODEL;
  const unsigned short* Bb = B + (size_t)bn * DMODEL;

  f32x4 acc[4][4];
#pragma unroll
  for (int i = 0; i < 4; ++i)
#pragma unroll
    for (int j = 0; j < 4; ++j) acc[i][j] = f32x4{0.f, 0.f, 0.f, 0.f};

#define STAGE(sb, ks)                                                         \
  do {                                                                        \
    GLD16(Ab + (size_t)r0 * DMODEL + (ks) + kc0 * 8, &As[sb][kc0][r0][0]);    \
    GLD16(Ab + (size_t)r1 * DMODEL + (ks) + kc1 * 8, &As[sb][kc1][r1][0]);    \
    GLD16(Bb + (size_t)r0 * DMODEL + (ks) + kc0 * 8, &Bs[sb][kc0][r0][0]);    \
    GLD16(Bb + (size_t)r1 * DMODEL + (ks) + kc1 * 8, &Bs[sb][kc1][r1][0]);    \
  } while (0)

#define COMPUTE(cb)                                                           \
  do {                                                                        \
    bf16x8 af[4], bf[4];                                                      \
    _Pragma("unroll")                                                         \
    for (int i = 0; i < 4; ++i)                                               \
      af[i] = *(const bf16x8*)(&As[cb][quad][wm + i * 16 + l16][0]);          \
    _Pragma("unroll")                                                         \
    for (int j = 0; j < 4; ++j)                                               \
      bf[j] = *(const bf16x8*)(&Bs[cb][quad][wn + j * 16 + l16][0]);          \
    __builtin_amdgcn_s_setprio(1);                                            \
    _Pragma("unroll")                                                         \
    for (int i = 0; i < 4; ++i)                                               \
      _Pragma("unroll")                                                       \
      for (int j = 0; j < 4; ++j)                                             \
        acc[i][j] = __builtin_amdgcn_mfma_f32_16x16x32_bf16(af[i], bf[j],     \
                                                            acc[i][j], 0, 0, 0); \
    __builtin_amdgcn_s_setprio(0);                                            \
  } while (0)

#define STEP(cb, sb, ks)                                                      \
  do {                                                                        \
    STAGE(sb, ks);                                                            \
    COMPUTE(cb);                                                              \
    asm volatile("s_waitcnt vmcnt(4)" ::: "memory");                          \
    __builtin_amdgcn_s_barrier();                                             \
  } while (0)

  // prologue: stage steps 0,1
  STAGE(0, 0);
  STAGE(1, 32);
  asm volatile("s_waitcnt vmcnt(4) lgkmcnt(0)" ::: "memory");
  __builtin_amdgcn_s_barrier();

#pragma unroll 1
  for (int t = 0; t < 10; ++t) {
    const int ks = t * 96;
    STEP(0, 2, ks + 64);    // step 3t:   compute buf0, stage step 3t+2
    STEP(1, 0, ks + 96);    // step 3t+1: compute buf1, stage step 3t+3
    STEP(2, 1, ks + 128);   // step 3t+2: compute buf2, stage step 3t+4
  }
  // epilogue steps 30, 31 (no staging left)
  COMPUTE(0);
  asm volatile("s_waitcnt vmcnt(0)" ::: "memory");
  __builtin_amdgcn_s_barrier();
  COMPUTE(1);

#undef STEP
#undef COMPUTE
#undef STAGE

  // zero this block's 128x128 z tile (replaces global memset; overlaps epilogue)
  {
    float* zt = out_z + (size_t)bm * DDICT + bn;
    const float4 z4 = make_float4(0.f, 0.f, 0.f, 0.f);
#pragma unroll
    for (int s = 0; s < 16; ++s) {
      int p = s * 256 + tid;          // 4096 float4 positions in 128x128 tile
      int rr = p >> 5, cc = p & 31;   // 32 float4 per row
      ((float4*)(zt + (size_t)rr * DDICT))[cc] = z4;
    }
  }

  // threshold epilogue: m = bm + wm + i*16 + quad*4 + r, n = bn + wn + j*16 + l16
#pragma unroll
  for (int j = 0; j < 4; ++j) {
    int coll = wn + j * 16 + l16;
    float bv = bias[bn + coll];
#pragma unroll
    for (int i = 0; i < 4; ++i)
#pragma unroll
      for (int r = 0; r < 4; ++r) {
        int rl = wm + i * 16 + quad * 4 + r;
        float z = acc[i][j][r] + bv;
        if (__builtin_fabsf(z) >= taus[rl]) {
          int row = bm + rl;
          unsigned p = atomicAdd(&cnt[row], 1u);
          if (p < MAXC)
            cand[(size_t)row * MAXC + p] = make_int2(bn + coll, __float_as_int(z));
        }
      }
  }
}

// ---------------------------------------------------------------- select + refine + decode
__global__ __launch_bounds__(256) void select_kernel(
    const float* __restrict__ x,
    const float* __restrict__ Wenc,
    const float* __restrict__ benc,
    const float* __restrict__ WdT,
    const float* __restrict__ bdec,
    const unsigned* __restrict__ cnt,
    const int2* __restrict__ cand,
    float* __restrict__ out_recon,
    float* __restrict__ out_z) {
  const int row  = blockIdx.x;
  const int tid  = threadIdx.x;
  const int lane = tid & 63;
  const int wave = tid >> 6;

  __shared__ float  xs[DMODEL];    // 4 KB
  __shared__ int    s_fcol[TOPK];
  __shared__ float  s_fval[TOPK];
  __shared__ int    s_acol[MAXA];
  __shared__ double s_adval[MAXA];
  __shared__ int    s_nI, s_nA;

  ((float4*)xs)[tid] = ((const float4*)(x + (size_t)row * DMODEL))[tid];
  if (tid == 0) { s_nI = 0; s_nA = 0; }

  int n = (int)cnt[row];
  if (n > MAXC) n = MAXC;

  unsigned key = 0; int mycol = -1; float myval = 0.f;
  if (tid < n) {
    int2 cv = cand[(size_t)row * MAXC + tid];
    mycol = cv.x;
    myval = __int_as_float(cv.y);
    key = (unsigned)cv.y & 0x7FFFFFFFu;
  }
  const float myabs = __uint_as_float(key);
  __syncthreads();

  // bit-bisect the 32nd-largest approx |z|
  const int nw = n < TOPK ? n : TOPK;
  unsigned lo = 0u, hi = 0x7F800000u;
  for (int it = 0; it < 28; ++it) {
    unsigned mid = (lo + hi) >> 1;
    int tot = __syncthreads_count((tid < n) && key >= mid);
    if (tot >= nw) lo = mid; else hi = mid;
  }
  const float t32 = __uint_as_float(lo);

  const bool sure_in = (tid < n) && (myabs > t32 + DELTA);
  const bool amb     = (tid < n) && !sure_in && (myabs >= t32 - DELTA);
  if (sure_in) {
    int p = atomicAdd(&s_nI, 1);
    if (p < TOPK) { s_fcol[p] = mycol; s_fval[p] = myval; }
  }
  if (amb) {
    int p = atomicAdd(&s_nA, 1);
    if (p < MAXA) s_acol[p] = mycol;
  }
  __syncthreads();
  int nI = s_nI < TOPK ? s_nI : TOPK;
  int nA = s_nA < MAXA ? s_nA : MAXA;
  int need = TOPK - nI;
  if (need < 0) need = 0;
  if (need > nA) need = nA;
  const int ntot = nI + need;

  // exact fp64 dots for ambiguous candidates (one wave per candidate)
  for (int c = wave; c < nA; c += 4) {
    const int j = s_acol[c];
    const float* wr = Wenc + (size_t)j * DMODEL;
    double s = 0.0;
#pragma unroll
    for (int t = 0; t < 16; ++t)
      s += (double)xs[lane + t * 64] * (double)wr[lane + t * 64];
#pragma unroll
    for (int off = 32; off; off >>= 1) s += __shfl_down(s, off);
    if (lane == 0) s_adval[c] = s + (double)benc[j];
  }
  __syncthreads();

  // pick top-`need` ambiguous by exact |val| (tie: lower dict index); nA<=64
  if (wave == 0) {
    bool alive = lane < nA;
    double dv = alive ? s_adval[lane] : 0.0;
    double va = alive ? fabs(dv) : -1.0;
    int    jj = alive ? s_acol[lane] : 0x7FFFFFFF;
    for (int pick = 0; pick < need; ++pick) {
      double ba = alive ? va : -1.0;
      int bj = alive ? jj : 0x7FFFFFFF;
      int bl = lane;
#pragma unroll
      for (int off = 32; off; off >>= 1) {
        double oa = __shfl_down(ba, off);
        int    oj = __shfl_down(bj, off);
        int    ol = __shfl_down(bl, off);
        if (oa > ba || (oa == ba && oj < bj)) { ba = oa; bj = oj; bl = ol; }
      }
      bl = __shfl(bl, 0);
      if (lane == bl) {
        alive = false;
        s_fcol[nI + pick] = jj;
        s_fval[nI + pick] = (float)dv;
      }
    }
  }
  __syncthreads();

  // scatter into pre-zeroed z (zeroed by gemm epilogue)
  if (tid < ntot)
    out_z[(size_t)row * DDICT + s_fcol[tid]] = s_fval[tid];

  // fused sparse decode; thread owns dims [4*tid, 4*tid+3]
  float a0, a1, a2, a3;
  {
    float4 b4 = ((const float4*)bdec)[tid];
    a0 = b4.x; a1 = b4.y; a2 = b4.z; a3 = b4.w;
  }
  for (int p = 0; p < ntot; ++p) {
    int j = s_fcol[p];
    float zv = s_fval[p];
    float4 wv = ((const float4*)(WdT + (size_t)j * DMODEL))[tid];
    a0 = fmaf(zv, wv.x, a0); a1 = fmaf(zv, wv.y, a1);
    a2 = fmaf(zv, wv.z, a2); a3 = fmaf(zv, wv.w, a3);
  }
  ((float4*)(out_recon + (size_t)row * DMODEL))[tid] = make_float4(a0, a1, a2, a3);
}

// ---------------------------------------------------------------- launch
extern "C" void kernel_launch(void* const* d_in, const int* in_sizes, int n_in,
                              void* d_out, int out_size, void* d_ws, size_t ws_size,
                              hipStream_t stream) {
  const float* x    = (const float*)d_in[0];
  const float* Wenc = (const float*)d_in[1];
  const float* benc = (const float*)d_in[2];
  const float* Wdec = (const float*)d_in[3];
  const float* bdec = (const float*)d_in[4];

  float* out_recon = (float*)d_out;
  float* out_z     = (float*)d_out + (size_t)M_TOK * DMODEL;

  // ws carve: xbf 16MB | wbf 33.5MB | wdT 67MB | cand 16.8MB | tau 32KB | cnt 32KB
  char* w = (char*)d_ws;
  unsigned short* xbf = (unsigned short*)w;                 w += (size_t)M_TOK * DMODEL * 2;
  unsigned short* wbf = (unsigned short*)w;                 w += (size_t)DDICT * DMODEL * 2;
  float*          wdT = (float*)w;                          w += (size_t)DDICT * DMODEL * 4;
  int2*           cand = (int2*)w;                          w += (size_t)M_TOK * MAXC * 8;
  float*          tau = (float*)w;                          w += (size_t)M_TOK * 4;
  unsigned*       cnt = (unsigned*)w;

  hipMemsetAsync(cnt, 0, (size_t)M_TOK * 4, stream);
  // out_z zero-fill is fused into gemm_enc_kernel's epilogue.

  cast_x_norm_kernel<<<M_TOK, 256, 0, stream>>>(x, xbf, tau);
  {
    int n4 = DDICT * DMODEL / 4;
    cast_bf16_kernel<<<(n4 + 255) / 256, 256, 0, stream>>>(Wenc, wbf, n4);
  }
  {
    dim3 g(DDICT / 32, DMODEL / 32);
    transpose_kernel<<<g, 256, 0, stream>>>(Wdec, wdT);
  }
  {
    // 8192 blocks = (DDICT/128) * (M_TOK/128); XCD-bijective decode in-kernel
    gemm_enc_kernel<<<(DDICT / 128) * (M_TOK / 128), 256, 0, stream>>>(
        xbf, wbf, benc, tau, cnt, cand, out_z);
  }
  select_kernel<<<M_TOK, 256, 0, stream>>>(x, Wenc, benc, wdT, bdec, cnt, cand,
                                           out_recon, out_z);
}

// Round 3
// 1487.359 us; speedup vs baseline: 1.0208x; 1.0208x over previous
//
#include <hip/hip_runtime.h>
#include <stdint.h>

#define M_TOK   8192
#define DMODEL  1024
#define DDICT   16384
#define TOPK    32
#define MAXC    256     // per-row candidate capacity (E[cnt]~98, P(>256)~0)
#define DELTA   0.03f   // certainty margin vs bf16-GEMM error (sigma ~1e-3)

typedef __attribute__((ext_vector_type(8))) short bf16x8;
typedef __attribute__((ext_vector_type(4))) float f32x4;

// ---------------------------------------------------------------- helpers
__device__ __forceinline__ unsigned short f32_to_bf16(float f) {
  unsigned u = __float_as_uint(f);
  unsigned r = 0x7FFFu + ((u >> 16) & 1u);   // round-to-nearest-even
  return (unsigned short)((u + r) >> 16);
}

#define GLD16(g, l)                                                        \
  __builtin_amdgcn_global_load_lds(                                        \
      (const __attribute__((address_space(1))) void*)(g),                  \
      (__attribute__((address_space(3))) void*)(l), 16, 0, 0)

// ---------------------------------------------------------------- x cast + row norm -> tau
__global__ __launch_bounds__(256) void cast_x_norm_kernel(
    const float* __restrict__ x, unsigned short* __restrict__ xbf,
    float* __restrict__ tau) {
  const int row = blockIdx.x, tid = threadIdx.x;
  const int lane = tid & 63, wave = tid >> 6;
  __shared__ float red[4];
  float4 v = ((const float4*)(x + (size_t)row * DMODEL))[tid];
  ushort4 o;
  o.x = f32_to_bf16(v.x); o.y = f32_to_bf16(v.y);
  o.z = f32_to_bf16(v.z); o.w = f32_to_bf16(v.w);
  ((ushort4*)(xbf + (size_t)row * DMODEL))[tid] = o;
  float ss = v.x * v.x + v.y * v.y + v.z * v.z + v.w * v.w;
#pragma unroll
  for (int off = 32; off; off >>= 1) ss += __shfl_down(ss, off);
  if (lane == 0) red[wave] = ss;
  __syncthreads();
  if (tid == 0) tau[row] = 0.055f * sqrtf(red[0] + red[1] + red[2] + red[3]);
}

// ---------------------------------------------------------------- Wenc cast
__global__ __launch_bounds__(256) void cast_bf16_kernel(
    const float* __restrict__ in, unsigned short* __restrict__ out, int n4) {
  int i = blockIdx.x * 256 + threadIdx.x;
  if (i >= n4) return;
  float4 v = ((const float4*)in)[i];
  ushort4 o;
  o.x = f32_to_bf16(v.x); o.y = f32_to_bf16(v.y);
  o.z = f32_to_bf16(v.z); o.w = f32_to_bf16(v.w);
  ((ushort4*)out)[i] = o;
}

// W_dec [DMODEL, DDICT] -> W_decT [DDICT, DMODEL]
__global__ __launch_bounds__(256) void transpose_kernel(
    const float* __restrict__ in, float* __restrict__ out) {
  __shared__ float tile[32][33];
  int tx = threadIdx.x & 31;
  int ty = threadIdx.x >> 5;
  int c0 = blockIdx.x * 32;
  int r0 = blockIdx.y * 32;
#pragma unroll
  for (int i = 0; i < 32; i += 8)
    tile[ty + i][tx] = in[(size_t)(r0 + ty + i) * DDICT + c0 + tx];
  __syncthreads();
#pragma unroll
  for (int i = 0; i < 32; i += 8)
    out[(size_t)(c0 + ty + i) * DMODEL + r0 + tx] = tile[tx][ty + i];
}

// ---------------------------------------------------------------- encoder GEMM + threshold epilogue
// Round-1 proven structure (best measured GEMM family member): block 128x256,
// 4 waves, wave strip 64 cols, 8x4 MFMA 16x16x32. A double-buffered in LDS via
// global_load_lds (kc-major, conflict-free); B direct global->reg per-lane
// (row-major == A-frag layout), statically double-buffered b0/b1, counted
// vmcnt(4) + raw barrier per 32-K phase (A stores drain; B loads span phases).
// z-fill removed (moved to select) -- this kernel is pure GEMM + threshold.
__global__ __launch_bounds__(256, 2) void gemm_enc_kernel(
    const unsigned short* __restrict__ A,
    const unsigned short* __restrict__ B,
    const float* __restrict__ bias,
    const float* __restrict__ tau,
    unsigned* __restrict__ cnt,
    int2* __restrict__ cand) {
  __shared__ __align__(16) unsigned short As[2][4][128][8];  // 16 KB dbuf
  __shared__ float taus[128];

  const int tid  = threadIdx.x;
  const int lane = tid & 63;
  const int wave = tid >> 6;
  const int l16  = lane & 15;
  const int quad = lane >> 4;

  const int bm = blockIdx.y * 128;
  const int bn = blockIdx.x * 256;
  const int n0 = wave * 64;            // wave's col strip (block-local)

  if (tid < 128) taus[tid] = tau[bm + tid];

  // A staging: 512 chunks of 16B per K-step, 2 per thread, kc-major layout
  const int c0 = tid, c1 = tid + 256;
  const int kc0 = c0 >> 7, r0 = c0 & 127;
  const int kc1 = c1 >> 7, r1 = c1 & 127;
  const unsigned short* Ab = A + (size_t)bm * DMODEL;

  // B row pointers: frag j, lane reads 16B at [col][k0 + quad*8]
  const unsigned short* Bp[4];
#pragma unroll
  for (int j = 0; j < 4; ++j)
    Bp[j] = B + (size_t)(bn + n0 + j * 16 + l16) * DMODEL + quad * 8;

  f32x4 acc[8][4];
#pragma unroll
  for (int i = 0; i < 8; ++i)
#pragma unroll
    for (int j = 0; j < 4; ++j) acc[i][j] = f32x4{0.f, 0.f, 0.f, 0.f};

  bf16x8 b0[4], b1[4];

  // prologue: stage A(k=0) -> As[0], load B(k=0) -> b0
  GLD16(Ab + (size_t)r0 * DMODEL + kc0 * 8, &As[0][kc0][r0][0]);
  GLD16(Ab + (size_t)r1 * DMODEL + kc1 * 8, &As[0][kc1][r1][0]);
  __builtin_amdgcn_sched_barrier(0);
#pragma unroll
  for (int j = 0; j < 4; ++j) b0[j] = *(const bf16x8*)(Bp[j]);
  __builtin_amdgcn_sched_barrier(0);
  asm volatile("s_waitcnt vmcnt(4)" ::: "memory");  // drain A stores, keep B in flight
  __builtin_amdgcn_s_barrier();
  __builtin_amdgcn_sched_barrier(0);

#pragma unroll 1
  for (int k0 = 0; k0 < DMODEL; k0 += 64) {
    // ---- phase 0: compute [k0,k0+32) from As[0]/b0; prefetch k0+32 -> As[1]/b1
    GLD16(Ab + (size_t)r0 * DMODEL + (k0 + 32) + kc0 * 8, &As[1][kc0][r0][0]);
    GLD16(Ab + (size_t)r1 * DMODEL + (k0 + 32) + kc1 * 8, &As[1][kc1][r1][0]);
    __builtin_amdgcn_sched_barrier(0);   // pin: A stages are oldest vmem of phase
#pragma unroll
    for (int j = 0; j < 4; ++j) b1[j] = *(const bf16x8*)(Bp[j] + k0 + 32);
    __builtin_amdgcn_s_setprio(1);
#pragma unroll
    for (int i = 0; i < 8; ++i) {
      bf16x8 a = *(const bf16x8*)(&As[0][quad][i * 16 + l16][0]);
#pragma unroll
      for (int j = 0; j < 4; ++j)
        acc[i][j] = __builtin_amdgcn_mfma_f32_16x16x32_bf16(a, b0[j], acc[i][j], 0, 0, 0);
    }
    __builtin_amdgcn_s_setprio(0);
    __builtin_amdgcn_sched_barrier(0);
    asm volatile("s_waitcnt vmcnt(4)" ::: "memory");
    __builtin_amdgcn_s_barrier();
    __builtin_amdgcn_sched_barrier(0);

    // ---- phase 1: compute [k0+32,k0+64) from As[1]/b1; prefetch k0+64 -> As[0]/b0
    const bool more = (k0 + 64 < DMODEL);
    if (more) {
      GLD16(Ab + (size_t)r0 * DMODEL + (k0 + 64) + kc0 * 8, &As[0][kc0][r0][0]);
      GLD16(Ab + (size_t)r1 * DMODEL + (k0 + 64) + kc1 * 8, &As[0][kc1][r1][0]);
      __builtin_amdgcn_sched_barrier(0);
#pragma unroll
      for (int j = 0; j < 4; ++j) b0[j] = *(const bf16x8*)(Bp[j] + k0 + 64);
    }
    __builtin_amdgcn_s_setprio(1);
#pragma unroll
    for (int i = 0; i < 8; ++i) {
      bf16x8 a = *(const bf16x8*)(&As[1][quad][i * 16 + l16][0]);
#pragma unroll
      for (int j = 0; j < 4; ++j)
        acc[i][j] = __builtin_amdgcn_mfma_f32_16x16x32_bf16(a, b1[j], acc[i][j], 0, 0, 0);
    }
    __builtin_amdgcn_s_setprio(0);
    if (more) {
      __builtin_amdgcn_sched_barrier(0);
      asm volatile("s_waitcnt vmcnt(4)" ::: "memory");
      __builtin_amdgcn_s_barrier();
      __builtin_amdgcn_sched_barrier(0);
    }
  }

  // epilogue: m = i*16 + quad*4 + r (block-local), n = n0 + j*16 + l16
#pragma unroll
  for (int j = 0; j < 4; ++j) {
    int coll = n0 + j * 16 + l16;
    float bv = bias[bn + coll];
#pragma unroll
    for (int i = 0; i < 8; ++i)
#pragma unroll
      for (int r = 0; r < 4; ++r) {
        int rl = i * 16 + quad * 4 + r;
        float z = acc[i][j][r] + bv;
        if (__builtin_fabsf(z) >= taus[rl]) {
          int row = bm + rl;
          unsigned p = atomicAdd(&cnt[row], 1u);
          if (p < MAXC)
            cand[(size_t)row * MAXC + p] = make_int2(bn + coll, __float_as_int(z));
        }
      }
  }
}

// ---------------------------------------------------------------- select + refine + decode
// Wave-per-row, barrier-free rewrite. One 64-lane wave owns a full row:
//  - row z zero-fill issued first (fire-and-forget; vmcnt(0) orders it before
//    the final scatter)
//  - x row held in registers (16/lane, layout lane+t*64 == fp64-dot access)
//  - 28-step bit-bisect for the 32nd-largest |z| via __ballot/__popcll
//    (replaces 28 __syncthreads_count block barriers)
//  - ambiguous band (+-DELTA): exact fp64 dot per candidate, whole wave,
//    iterated over ballot bits; top-`need` picked by shuffle reduction
//    (exact |val| desc, tie lower index -- identical policy to before)
//  - decode: shuffle-broadcast (col,val) per selected entry, float4 gather of
//    WdT rows, accumulate in registers. No LDS, no __syncthreads anywhere.
__global__ __launch_bounds__(256) void select_kernel(
    const float* __restrict__ x,
    const float* __restrict__ Wenc,
    const float* __restrict__ benc,
    const float* __restrict__ WdT,
    const float* __restrict__ bdec,
    const unsigned* __restrict__ cnt,
    const int2* __restrict__ cand,
    float* __restrict__ out_recon,
    float* __restrict__ out_z) {
  const int lane = threadIdx.x & 63;
  const int wave = threadIdx.x >> 6;
  const int row  = blockIdx.x * 4 + wave;

  // ---- zero this row's z slice (4096 float4; 64 per lane), overlapped below
  float* zrow = out_z + (size_t)row * DDICT;
  {
    const float4 z4 = make_float4(0.f, 0.f, 0.f, 0.f);
#pragma unroll
    for (int t = 0; t < 64; ++t)
      ((float4*)zrow)[lane + t * 64] = z4;
  }

  // ---- x row into registers
  float xr[16];
  const float* xrow = x + (size_t)row * DMODEL;
#pragma unroll
  for (int t = 0; t < 16; ++t) xr[t] = xrow[lane + t * 64];

  // ---- candidates (4 slots per lane)
  int n = (int)cnt[row];
  if (n > MAXC) n = MAXC;
  int ccol[4]; float cval[4]; unsigned ckey[4]; bool act[4];
#pragma unroll
  for (int c = 0; c < 4; ++c) {
    const int idx = c * 64 + lane;
    act[c] = idx < n;
    ccol[c] = 0x7FFFFFFF; cval[c] = 0.f; ckey[c] = 0u;
    if (act[c]) {
      int2 cv = cand[(size_t)row * MAXC + idx];
      ccol[c] = cv.x;
      cval[c] = __int_as_float(cv.y);
      ckey[c] = (unsigned)cv.y & 0x7FFFFFFFu;
    }
  }

  // ---- bisect 32nd-largest approx |z| (wave-local, no barriers)
  const int nw = n < TOPK ? n : TOPK;
  unsigned lo = 0u, hi = 0x7F800000u;
  for (int it = 0; it < 28; ++it) {
    const unsigned mid = (lo + hi) >> 1;
    int tot = 0;
#pragma unroll
    for (int c = 0; c < 4; ++c)
      tot += __popcll(__ballot(act[c] && ckey[c] >= mid));
    if (tot >= nw) lo = mid; else hi = mid;
  }
  const float t32 = __uint_as_float(lo);

  // ---- membership flags
  bool fin[4], amb[4];
#pragma unroll
  for (int c = 0; c < 4; ++c) {
    const float ab = __uint_as_float(ckey[c]);
    fin[c] = act[c] && (ab > t32 + DELTA);
    amb[c] = act[c] && !fin[c] && (ab >= t32 - DELTA);
  }
  int nI = 0, nA = 0;
#pragma unroll
  for (int c = 0; c < 4; ++c) {
    nI += __popcll(__ballot(fin[c]));
    nA += __popcll(__ballot(amb[c]));
  }

  // ---- exact fp64 dots for every ambiguous candidate (whole wave each)
  double dval[4] = {0.0, 0.0, 0.0, 0.0};
#pragma unroll
  for (int c = 0; c < 4; ++c) {
    unsigned long long bits = __ballot(amb[c]);
    while (bits) {
      const int src = __ffsll(bits) - 1;
      bits &= bits - 1;
      const int j = __shfl(ccol[c], src);
      const float* wr = Wenc + (size_t)j * DMODEL;
      double s = 0.0;
#pragma unroll
      for (int t = 0; t < 16; ++t)
        s += (double)xr[t] * (double)wr[lane + t * 64];
#pragma unroll
      for (int off = 32; off; off >>= 1) s += __shfl_down(s, off);
      const double dv = __shfl(s, 0) + (double)benc[j];
      if (lane == src) {
#pragma unroll
        for (int cc = 0; cc < 4; ++cc)
          if (cc == c) dval[cc] = dv;
      }
    }
  }

  // ---- pick top-`need` ambiguous by exact |val| (tie: lower dict index)
  int need = TOPK - nI;
  if (need < 0) need = 0;
  if (need > nA) need = nA;
  for (int pick = 0; pick < need; ++pick) {
    double ba = -1.0; int bcol = 0x7FFFFFFF; int bslot = -1;
#pragma unroll
    for (int c = 0; c < 4; ++c)
      if (amb[c]) {
        const double va = fabs(dval[c]);
        if (va > ba || (va == ba && ccol[c] < bcol)) {
          ba = va; bcol = ccol[c]; bslot = c;
        }
      }
    int bl = lane;
#pragma unroll
    for (int off = 32; off; off >>= 1) {
      const double oa = __shfl_down(ba, off);
      const int    oc = __shfl_down(bcol, off);
      const int    ol = __shfl_down(bl, off);
      if (oa > ba || (oa == ba && oc < bcol)) { ba = oa; bcol = oc; bl = ol; }
    }
    bl = __shfl(bl, 0);
    if (lane == bl) {
      // winner lane: its local (ba,bslot) is the global winner; static-index update
#pragma unroll
      for (int c = 0; c < 4; ++c)
        if (c == bslot) {
          amb[c] = false;
          fin[c] = true;
          cval[c] = (float)dval[c];
        }
    }
  }

  // ---- fused sparse decode: lane owns float4 dims [lane+t*64], t=0..3
  float4 a[4];
#pragma unroll
  for (int t = 0; t < 4; ++t) a[t] = ((const float4*)bdec)[lane + t * 64];
#pragma unroll
  for (int c = 0; c < 4; ++c) {
    unsigned long long bits = __ballot(fin[c]);
    while (bits) {
      const int src = __ffsll(bits) - 1;
      bits &= bits - 1;
      const int   j  = __shfl(ccol[c], src);
      const float zv = __shfl(cval[c], src);
      const float4* wr4 = (const float4*)(WdT + (size_t)j * DMODEL);
#pragma unroll
      for (int t = 0; t < 4; ++t) {
        const float4 wv = wr4[lane + t * 64];
        a[t].x = fmaf(zv, wv.x, a[t].x);
        a[t].y = fmaf(zv, wv.y, a[t].y);
        a[t].z = fmaf(zv, wv.z, a[t].z);
        a[t].w = fmaf(zv, wv.w, a[t].w);
      }
    }
  }
  float4* rrow = (float4*)(out_recon + (size_t)row * DMODEL);
#pragma unroll
  for (int t = 0; t < 4; ++t) rrow[lane + t * 64] = a[t];

  // ---- z scatter (after zero-stores are retired: vmcnt covers them)
  asm volatile("s_waitcnt vmcnt(0)" ::: "memory");
#pragma unroll
  for (int c = 0; c < 4; ++c)
    if (fin[c]) zrow[ccol[c]] = cval[c];
}

// ---------------------------------------------------------------- launch
extern "C" void kernel_launch(void* const* d_in, const int* in_sizes, int n_in,
                              void* d_out, int out_size, void* d_ws, size_t ws_size,
                              hipStream_t stream) {
  const float* x    = (const float*)d_in[0];
  const float* Wenc = (const float*)d_in[1];
  const float* benc = (const float*)d_in[2];
  const float* Wdec = (const float*)d_in[3];
  const float* bdec = (const float*)d_in[4];

  float* out_recon = (float*)d_out;
  float* out_z     = (float*)d_out + (size_t)M_TOK * DMODEL;

  // ws carve: xbf 16MB | wbf 33.5MB | wdT 67MB | cand 16.8MB | tau 32KB | cnt 32KB
  char* w = (char*)d_ws;
  unsigned short* xbf = (unsigned short*)w;                 w += (size_t)M_TOK * DMODEL * 2;
  unsigned short* wbf = (unsigned short*)w;                 w += (size_t)DDICT * DMODEL * 2;
  float*          wdT = (float*)w;                          w += (size_t)DDICT * DMODEL * 4;
  int2*           cand = (int2*)w;                          w += (size_t)M_TOK * MAXC * 8;
  float*          tau = (float*)w;                          w += (size_t)M_TOK * 4;
  unsigned*       cnt = (unsigned*)w;

  hipMemsetAsync(cnt, 0, (size_t)M_TOK * 4, stream);
  // out_z zero-fill is fused into select_kernel (per-row, pre-scatter).

  cast_x_norm_kernel<<<M_TOK, 256, 0, stream>>>(x, xbf, tau);
  {
    int n4 = DDICT * DMODEL / 4;
    cast_bf16_kernel<<<(n4 + 255) / 256, 256, 0, stream>>>(Wenc, wbf, n4);
  }
  {
    dim3 g(DDICT / 32, DMODEL / 32);
    transpose_kernel<<<g, 256, 0, stream>>>(Wdec, wdT);
  }
  {
    dim3 g(DDICT / 256, M_TOK / 128);
    gemm_enc_kernel<<<g, 256, 0, stream>>>(xbf, wbf, benc, tau, cnt, cand);
  }
  select_kernel<<<M_TOK / 4, 256, 0, stream>>>(x, Wenc, benc, wdT, bdec, cnt, cand,
                                               out_recon, out_z);
}

// Round 4
// 1377.728 us; speedup vs baseline: 1.1020x; 1.0796x over previous
//
#include <hip/hip_runtime.h>
#include <stdint.h>

#define M_TOK   8192
#define DMODEL  1024
#define DDICT   16384
#define TOPK    32
#define MAXC    256     // per-row candidate capacity (E[cnt]~98, P(>256)~0)
#define DELTA   0.03f   // certainty margin vs bf16-GEMM error (sigma ~1e-3)

typedef __attribute__((ext_vector_type(8))) short bf16x8;
typedef __attribute__((ext_vector_type(4))) float f32x4;

// ---------------------------------------------------------------- helpers
__device__ __forceinline__ unsigned short f32_to_bf16(float f) {
  unsigned u = __float_as_uint(f);
  unsigned r = 0x7FFFu + ((u >> 16) & 1u);   // round-to-nearest-even
  return (unsigned short)((u + r) >> 16);
}

__device__ __forceinline__ float bf2f(unsigned short h) {
  return __uint_as_float(((unsigned)h) << 16);
}

#define GLD16(g, l)                                                        \
  __builtin_amdgcn_global_load_lds(                                        \
      (const __attribute__((address_space(1))) void*)(g),                  \
      (__attribute__((address_space(3))) void*)(l), 16, 0, 0)

// ---------------------------------------------------------------- x cast + row norm -> tau
__global__ __launch_bounds__(256) void cast_x_norm_kernel(
    const float* __restrict__ x, unsigned short* __restrict__ xbf,
    float* __restrict__ tau) {
  const int row = blockIdx.x, tid = threadIdx.x;
  const int lane = tid & 63, wave = tid >> 6;
  __shared__ float red[4];
  float4 v = ((const float4*)(x + (size_t)row * DMODEL))[tid];
  ushort4 o;
  o.x = f32_to_bf16(v.x); o.y = f32_to_bf16(v.y);
  o.z = f32_to_bf16(v.z); o.w = f32_to_bf16(v.w);
  ((ushort4*)(xbf + (size_t)row * DMODEL))[tid] = o;
  float ss = v.x * v.x + v.y * v.y + v.z * v.z + v.w * v.w;
#pragma unroll
  for (int off = 32; off; off >>= 1) ss += __shfl_down(ss, off);
  if (lane == 0) red[wave] = ss;
  __syncthreads();
  if (tid == 0) tau[row] = 0.055f * sqrtf(red[0] + red[1] + red[2] + red[3]);
}

// ---------------------------------------------------------------- Wenc cast
__global__ __launch_bounds__(256) void cast_bf16_kernel(
    const float* __restrict__ in, unsigned short* __restrict__ out, int n4) {
  int i = blockIdx.x * 256 + threadIdx.x;
  if (i >= n4) return;
  float4 v = ((const float4*)in)[i];
  ushort4 o;
  o.x = f32_to_bf16(v.x); o.y = f32_to_bf16(v.y);
  o.z = f32_to_bf16(v.z); o.w = f32_to_bf16(v.w);
  ((ushort4*)out)[i] = o;
}

// W_dec [DMODEL, DDICT] fp32 -> W_decT [DDICT, DMODEL] bf16
// (decode table halved: 67 MB -> 33.5 MB; gather traffic 1 GB -> 512 MB)
__global__ __launch_bounds__(256) void transpose_bf16_kernel(
    const float* __restrict__ in, unsigned short* __restrict__ out) {
  __shared__ float tile[32][33];
  int tx = threadIdx.x & 31;
  int ty = threadIdx.x >> 5;
  int c0 = blockIdx.x * 32;
  int r0 = blockIdx.y * 32;
#pragma unroll
  for (int i = 0; i < 32; i += 8)
    tile[ty + i][tx] = in[(size_t)(r0 + ty + i) * DDICT + c0 + tx];
  __syncthreads();
#pragma unroll
  for (int i = 0; i < 32; i += 8)
    out[(size_t)(c0 + ty + i) * DMODEL + r0 + tx] = f32_to_bf16(tile[tx][ty + i]);
}

// ---------------------------------------------------------------- encoder GEMM + threshold epilogue
// Round-1 proven structure (best measured): block 128x256, 4 waves, wave strip
// 64 cols, 8x4 MFMA 16x16x32. A double-buffered in LDS via global_load_lds
// (kc-major, conflict-free); B direct global->reg per-lane (row-major ==
// A-frag layout), statically double-buffered b0/b1, counted vmcnt(4) + raw
// barrier per 32-K phase. z-tile zero-fill fused in epilogue (r1-proven:
// overlaps the HBM-idle GEMM; gemm runs at ~6% HBM BW so stores are free-ish).
__global__ __launch_bounds__(256, 2) void gemm_enc_kernel(
    const unsigned short* __restrict__ A,
    const unsigned short* __restrict__ B,
    const float* __restrict__ bias,
    const float* __restrict__ tau,
    unsigned* __restrict__ cnt,
    int2* __restrict__ cand,
    float* __restrict__ out_z) {
  __shared__ __align__(16) unsigned short As[2][4][128][8];  // 16 KB dbuf
  __shared__ float taus[128];

  const int tid  = threadIdx.x;
  const int lane = tid & 63;
  const int wave = tid >> 6;
  const int l16  = lane & 15;
  const int quad = lane >> 4;

  const int bm = blockIdx.y * 128;
  const int bn = blockIdx.x * 256;
  const int n0 = wave * 64;            // wave's col strip (block-local)

  if (tid < 128) taus[tid] = tau[bm + tid];

  // A staging: 512 chunks of 16B per K-step, 2 per thread, kc-major layout
  const int c0 = tid, c1 = tid + 256;
  const int kc0 = c0 >> 7, r0 = c0 & 127;
  const int kc1 = c1 >> 7, r1 = c1 & 127;
  const unsigned short* Ab = A + (size_t)bm * DMODEL;

  // B row pointers: frag j, lane reads 16B at [col][k0 + quad*8]
  const unsigned short* Bp[4];
#pragma unroll
  for (int j = 0; j < 4; ++j)
    Bp[j] = B + (size_t)(bn + n0 + j * 16 + l16) * DMODEL + quad * 8;

  f32x4 acc[8][4];
#pragma unroll
  for (int i = 0; i < 8; ++i)
#pragma unroll
    for (int j = 0; j < 4; ++j) acc[i][j] = f32x4{0.f, 0.f, 0.f, 0.f};

  bf16x8 b0[4], b1[4];

  // prologue: stage A(k=0) -> As[0], load B(k=0) -> b0
  GLD16(Ab + (size_t)r0 * DMODEL + kc0 * 8, &As[0][kc0][r0][0]);
  GLD16(Ab + (size_t)r1 * DMODEL + kc1 * 8, &As[0][kc1][r1][0]);
  __builtin_amdgcn_sched_barrier(0);
#pragma unroll
  for (int j = 0; j < 4; ++j) b0[j] = *(const bf16x8*)(Bp[j]);
  __builtin_amdgcn_sched_barrier(0);
  asm volatile("s_waitcnt vmcnt(4)" ::: "memory");  // drain A stores, keep B in flight
  __builtin_amdgcn_s_barrier();
  __builtin_amdgcn_sched_barrier(0);

#pragma unroll 1
  for (int k0 = 0; k0 < DMODEL; k0 += 64) {
    // ---- phase 0: compute [k0,k0+32) from As[0]/b0; prefetch k0+32 -> As[1]/b1
    GLD16(Ab + (size_t)r0 * DMODEL + (k0 + 32) + kc0 * 8, &As[1][kc0][r0][0]);
    GLD16(Ab + (size_t)r1 * DMODEL + (k0 + 32) + kc1 * 8, &As[1][kc1][r1][0]);
    __builtin_amdgcn_sched_barrier(0);   // pin: A stages are oldest vmem of phase
#pragma unroll
    for (int j = 0; j < 4; ++j) b1[j] = *(const bf16x8*)(Bp[j] + k0 + 32);
    __builtin_amdgcn_s_setprio(1);
#pragma unroll
    for (int i = 0; i < 8; ++i) {
      bf16x8 a = *(const bf16x8*)(&As[0][quad][i * 16 + l16][0]);
#pragma unroll
      for (int j = 0; j < 4; ++j)
        acc[i][j] = __builtin_amdgcn_mfma_f32_16x16x32_bf16(a, b0[j], acc[i][j], 0, 0, 0);
    }
    __builtin_amdgcn_s_setprio(0);
    __builtin_amdgcn_sched_barrier(0);
    asm volatile("s_waitcnt vmcnt(4)" ::: "memory");
    __builtin_amdgcn_s_barrier();
    __builtin_amdgcn_sched_barrier(0);

    // ---- phase 1: compute [k0+32,k0+64) from As[1]/b1; prefetch k0+64 -> As[0]/b0
    const bool more = (k0 + 64 < DMODEL);
    if (more) {
      GLD16(Ab + (size_t)r0 * DMODEL + (k0 + 64) + kc0 * 8, &As[0][kc0][r0][0]);
      GLD16(Ab + (size_t)r1 * DMODEL + (k0 + 64) + kc1 * 8, &As[0][kc1][r1][0]);
      __builtin_amdgcn_sched_barrier(0);
#pragma unroll
      for (int j = 0; j < 4; ++j) b0[j] = *(const bf16x8*)(Bp[j] + k0 + 64);
    }
    __builtin_amdgcn_s_setprio(1);
#pragma unroll
    for (int i = 0; i < 8; ++i) {
      bf16x8 a = *(const bf16x8*)(&As[1][quad][i * 16 + l16][0]);
#pragma unroll
      for (int j = 0; j < 4; ++j)
        acc[i][j] = __builtin_amdgcn_mfma_f32_16x16x32_bf16(a, b1[j], acc[i][j], 0, 0, 0);
    }
    __builtin_amdgcn_s_setprio(0);
    if (more) {
      __builtin_amdgcn_sched_barrier(0);
      asm volatile("s_waitcnt vmcnt(4)" ::: "memory");
      __builtin_amdgcn_s_barrier();
      __builtin_amdgcn_sched_barrier(0);
    }
  }

  // zero this block's 128x256 z tile (fire-and-forget; overlaps epilogue ALU;
  // cross-kernel ordering guarantees completion before select's scatter)
  {
    float* zt = out_z + (size_t)bm * DDICT + bn;
    const float4 z4 = make_float4(0.f, 0.f, 0.f, 0.f);
#pragma unroll
    for (int s = 0; s < 32; ++s) {
      int p = s * 256 + tid;          // 8192 float4 positions in 128x256 tile
      int rr = p >> 6, cc = p & 63;   // 64 float4 per row
      ((float4*)(zt + (size_t)rr * DDICT))[cc] = z4;
    }
  }

  // epilogue: m = i*16 + quad*4 + r (block-local), n = n0 + j*16 + l16
#pragma unroll
  for (int j = 0; j < 4; ++j) {
    int coll = n0 + j * 16 + l16;
    float bv = bias[bn + coll];
#pragma unroll
    for (int i = 0; i < 8; ++i)
#pragma unroll
      for (int r = 0; r < 4; ++r) {
        int rl = i * 16 + quad * 4 + r;
        float z = acc[i][j][r] + bv;
        if (__builtin_fabsf(z) >= taus[rl]) {
          int row = bm + rl;
          unsigned p = atomicAdd(&cnt[row], 1u);
          if (p < MAXC)
            cand[(size_t)row * MAXC + p] = make_int2(bn + coll, __float_as_int(z));
        }
      }
  }
}

// ---------------------------------------------------------------- select + refine + decode
// Wave-per-row, barrier-free (r3 structure), now byte-trimmed:
//  - z zero-fill moved back to gemm (HBM-idle kernel)
//  - decode gathers bf16 WdT rows (2 KB/feature instead of 4 KB)
//  - x / Wenc refine loads as float4 (4 vmem per KB instead of 16)
// Selection policy unchanged: 28-step bisect on bf16-GEMM |z| keys, +-DELTA
// band refined with exact fp64 dots vs fp32 Wenc, tie -> lower dict index.
__global__ __launch_bounds__(256) void select_kernel(
    const float* __restrict__ x,
    const float* __restrict__ Wenc,
    const float* __restrict__ benc,
    const unsigned short* __restrict__ wdTb,
    const float* __restrict__ bdec,
    const unsigned* __restrict__ cnt,
    const int2* __restrict__ cand,
    float* __restrict__ out_recon,
    float* __restrict__ out_z) {
  const int lane = threadIdx.x & 63;
  const int wave = threadIdx.x >> 6;
  const int row  = blockIdx.x * 4 + wave;

  // ---- x row into registers as float4 (lane covers dims [lane*4 + t*256 ..])
  float4 x4[4];
  const float4* xrow4 = (const float4*)(x + (size_t)row * DMODEL);
#pragma unroll
  for (int t = 0; t < 4; ++t) x4[t] = xrow4[lane + t * 64];

  // ---- candidates (4 slots per lane)
  int n = (int)cnt[row];
  if (n > MAXC) n = MAXC;
  int ccol[4]; float cval[4]; unsigned ckey[4]; bool act[4];
#pragma unroll
  for (int c = 0; c < 4; ++c) {
    const int idx = c * 64 + lane;
    act[c] = idx < n;
    ccol[c] = 0x7FFFFFFF; cval[c] = 0.f; ckey[c] = 0u;
    if (act[c]) {
      int2 cv = cand[(size_t)row * MAXC + idx];
      ccol[c] = cv.x;
      cval[c] = __int_as_float(cv.y);
      ckey[c] = (unsigned)cv.y & 0x7FFFFFFFu;
    }
  }

  // ---- bisect 32nd-largest approx |z| (wave-local, no barriers)
  const int nw = n < TOPK ? n : TOPK;
  unsigned lo = 0u, hi = 0x7F800000u;
  for (int it = 0; it < 28; ++it) {
    const unsigned mid = (lo + hi) >> 1;
    int tot = 0;
#pragma unroll
    for (int c = 0; c < 4; ++c)
      tot += __popcll(__ballot(act[c] && ckey[c] >= mid));
    if (tot >= nw) lo = mid; else hi = mid;
  }
  const float t32 = __uint_as_float(lo);

  // ---- membership flags
  bool fin[4], amb[4];
#pragma unroll
  for (int c = 0; c < 4; ++c) {
    const float ab = __uint_as_float(ckey[c]);
    fin[c] = act[c] && (ab > t32 + DELTA);
    amb[c] = act[c] && !fin[c] && (ab >= t32 - DELTA);
  }
  int nI = 0, nA = 0;
#pragma unroll
  for (int c = 0; c < 4; ++c) {
    nI += __popcll(__ballot(fin[c]));
    nA += __popcll(__ballot(amb[c]));
  }

  // ---- exact fp64 dots for every ambiguous candidate (whole wave each)
  double dval[4] = {0.0, 0.0, 0.0, 0.0};
#pragma unroll
  for (int c = 0; c < 4; ++c) {
    unsigned long long bits = __ballot(amb[c]);
    while (bits) {
      const int src = __ffsll(bits) - 1;
      bits &= bits - 1;
      const int j = __shfl(ccol[c], src);
      const float4* wr4 = (const float4*)(Wenc + (size_t)j * DMODEL);
      double s = 0.0;
#pragma unroll
      for (int t = 0; t < 4; ++t) {
        const float4 wv = wr4[lane + t * 64];
        s += (double)x4[t].x * (double)wv.x + (double)x4[t].y * (double)wv.y +
             (double)x4[t].z * (double)wv.z + (double)x4[t].w * (double)wv.w;
      }
#pragma unroll
      for (int off = 32; off; off >>= 1) s += __shfl_down(s, off);
      const double dv = __shfl(s, 0) + (double)benc[j];
      if (lane == src) {
#pragma unroll
        for (int cc = 0; cc < 4; ++cc)
          if (cc == c) dval[cc] = dv;
      }
    }
  }

  // ---- pick top-`need` ambiguous by exact |val| (tie: lower dict index)
  int need = TOPK - nI;
  if (need < 0) need = 0;
  if (need > nA) need = nA;
  for (int pick = 0; pick < need; ++pick) {
    double ba = -1.0; int bcol = 0x7FFFFFFF; int bslot = -1;
#pragma unroll
    for (int c = 0; c < 4; ++c)
      if (amb[c]) {
        const double va = fabs(dval[c]);
        if (va > ba || (va == ba && ccol[c] < bcol)) {
          ba = va; bcol = ccol[c]; bslot = c;
        }
      }
    int bl = lane;
#pragma unroll
    for (int off = 32; off; off >>= 1) {
      const double oa = __shfl_down(ba, off);
      const int    oc = __shfl_down(bcol, off);
      const int    ol = __shfl_down(bl, off);
      if (oa > ba || (oa == ba && oc < bcol)) { ba = oa; bcol = oc; bl = ol; }
    }
    bl = __shfl(bl, 0);
    if (lane == bl) {
      // winner lane: its local (ba,bslot) is the global winner; static-index update
#pragma unroll
      for (int c = 0; c < 4; ++c)
        if (c == bslot) {
          amb[c] = false;
          fin[c] = true;
          cval[c] = (float)dval[c];
        }
    }
  }

  // ---- fused sparse decode from bf16 WdT; lane owns dims [8*lane..8*lane+7]
  //      and [512+8*lane..512+8*lane+7]
  float ax[16];
  {
    const float4* b4 = (const float4*)bdec;
    float4 t0 = b4[2 * lane],       t1 = b4[2 * lane + 1];
    float4 t2 = b4[128 + 2 * lane], t3 = b4[129 + 2 * lane];
    ax[0] = t0.x; ax[1] = t0.y; ax[2]  = t0.z; ax[3]  = t0.w;
    ax[4] = t1.x; ax[5] = t1.y; ax[6]  = t1.z; ax[7]  = t1.w;
    ax[8] = t2.x; ax[9] = t2.y; ax[10] = t2.z; ax[11] = t2.w;
    ax[12] = t3.x; ax[13] = t3.y; ax[14] = t3.z; ax[15] = t3.w;
  }
#pragma unroll
  for (int c = 0; c < 4; ++c) {
    unsigned long long bits = __ballot(fin[c]);
    while (bits) {
      const int src = __ffsll(bits) - 1;
      bits &= bits - 1;
      const int   j  = __shfl(ccol[c], src);
      const float zv = __shfl(cval[c], src);
      const unsigned short* wrow = wdTb + (size_t)j * DMODEL;
      bf16x8 w0 = ((const bf16x8*)wrow)[lane];
      bf16x8 w1 = ((const bf16x8*)wrow)[lane + 64];
#pragma unroll
      for (int k = 0; k < 8; ++k) {
        ax[k]     = fmaf(zv, bf2f((unsigned short)w0[k]), ax[k]);
        ax[8 + k] = fmaf(zv, bf2f((unsigned short)w1[k]), ax[8 + k]);
      }
    }
  }
  {
    float4* r4 = (float4*)(out_recon + (size_t)row * DMODEL);
    r4[2 * lane]       = make_float4(ax[0], ax[1], ax[2], ax[3]);
    r4[2 * lane + 1]   = make_float4(ax[4], ax[5], ax[6], ax[7]);
    r4[128 + 2 * lane] = make_float4(ax[8], ax[9], ax[10], ax[11]);
    r4[129 + 2 * lane] = make_float4(ax[12], ax[13], ax[14], ax[15]);
  }

  // ---- z scatter (tile pre-zeroed by gemm; cross-kernel order guarantees it)
  float* zrow = out_z + (size_t)row * DDICT;
#pragma unroll
  for (int c = 0; c < 4; ++c)
    if (fin[c]) zrow[ccol[c]] = cval[c];
}

// ---------------------------------------------------------------- launch
extern "C" void kernel_launch(void* const* d_in, const int* in_sizes, int n_in,
                              void* d_out, int out_size, void* d_ws, size_t ws_size,
                              hipStream_t stream) {
  const float* x    = (const float*)d_in[0];
  const float* Wenc = (const float*)d_in[1];
  const float* benc = (const float*)d_in[2];
  const float* Wdec = (const float*)d_in[3];
  const float* bdec = (const float*)d_in[4];

  float* out_recon = (float*)d_out;
  float* out_z     = (float*)d_out + (size_t)M_TOK * DMODEL;

  // ws carve: xbf 16MB | wbf 33.5MB | wdTb 33.5MB | cand 16.8MB | tau 32KB | cnt 32KB
  char* w = (char*)d_ws;
  unsigned short* xbf  = (unsigned short*)w;                w += (size_t)M_TOK * DMODEL * 2;
  unsigned short* wbf  = (unsigned short*)w;                w += (size_t)DDICT * DMODEL * 2;
  unsigned short* wdTb = (unsigned short*)w;                w += (size_t)DDICT * DMODEL * 2;
  int2*           cand = (int2*)w;                          w += (size_t)M_TOK * MAXC * 8;
  float*          tau  = (float*)w;                         w += (size_t)M_TOK * 4;
  unsigned*       cnt  = (unsigned*)w;

  hipMemsetAsync(cnt, 0, (size_t)M_TOK * 4, stream);
  // out_z zero-fill is fused into gemm_enc_kernel's epilogue.

  cast_x_norm_kernel<<<M_TOK, 256, 0, stream>>>(x, xbf, tau);
  {
    int n4 = DDICT * DMODEL / 4;
    cast_bf16_kernel<<<(n4 + 255) / 256, 256, 0, stream>>>(Wenc, wbf, n4);
  }
  {
    dim3 g(DDICT / 32, DMODEL / 32);
    transpose_bf16_kernel<<<g, 256, 0, stream>>>(Wdec, wdTb);
  }
  {
    dim3 g(DDICT / 256, M_TOK / 128);
    gemm_enc_kernel<<<g, 256, 0, stream>>>(xbf, wbf, benc, tau, cnt, cand, out_z);
  }
  select_kernel<<<M_TOK / 4, 256, 0, stream>>>(x, Wenc, benc, wdTb, bdec, cnt, cand,
                                               out_recon, out_z);
}

// Round 5
// 1342.129 us; speedup vs baseline: 1.1313x; 1.0265x over previous
//
#include <hip/hip_runtime.h>
#include <stdint.h>

#define M_TOK   8192
#define DMODEL  1024
#define DDICT   16384
#define TOPK    32
#define MAXC    256     // per-row candidate capacity (E[cnt]~98, P(>256)~0)
#define DELTA   0.03f   // certainty margin vs bf16-GEMM error (sigma ~1e-3)

typedef __attribute__((ext_vector_type(8))) short bf16x8;
typedef __attribute__((ext_vector_type(4))) float f32x4;

// ---------------------------------------------------------------- helpers
__device__ __forceinline__ unsigned short f32_to_bf16(float f) {
  unsigned u = __float_as_uint(f);
  unsigned r = 0x7FFFu + ((u >> 16) & 1u);   // round-to-nearest-even
  return (unsigned short)((u + r) >> 16);
}

__device__ __forceinline__ float bf2f(unsigned short h) {
  return __uint_as_float(((unsigned)h) << 16);
}

#define GLD16(g, l)                                                        \
  __builtin_amdgcn_global_load_lds(                                        \
      (const __attribute__((address_space(1))) void*)(g),                  \
      (__attribute__((address_space(3))) void*)(l), 16, 0, 0)

// ---------------------------------------------------------------- x cast + row norm -> tau
__global__ __launch_bounds__(256) void cast_x_norm_kernel(
    const float* __restrict__ x, unsigned short* __restrict__ xbf,
    float* __restrict__ tau) {
  const int row = blockIdx.x, tid = threadIdx.x;
  const int lane = tid & 63, wave = tid >> 6;
  __shared__ float red[4];
  float4 v = ((const float4*)(x + (size_t)row * DMODEL))[tid];
  ushort4 o;
  o.x = f32_to_bf16(v.x); o.y = f32_to_bf16(v.y);
  o.z = f32_to_bf16(v.z); o.w = f32_to_bf16(v.w);
  ((ushort4*)(xbf + (size_t)row * DMODEL))[tid] = o;
  float ss = v.x * v.x + v.y * v.y + v.z * v.z + v.w * v.w;
#pragma unroll
  for (int off = 32; off; off >>= 1) ss += __shfl_down(ss, off);
  if (lane == 0) red[wave] = ss;
  __syncthreads();
  if (tid == 0) tau[row] = 0.055f * sqrtf(red[0] + red[1] + red[2] + red[3]);
}

// ---------------------------------------------------------------- Wenc cast
__global__ __launch_bounds__(256) void cast_bf16_kernel(
    const float* __restrict__ in, unsigned short* __restrict__ out, int n4) {
  int i = blockIdx.x * 256 + threadIdx.x;
  if (i >= n4) return;
  float4 v = ((const float4*)in)[i];
  ushort4 o;
  o.x = f32_to_bf16(v.x); o.y = f32_to_bf16(v.y);
  o.z = f32_to_bf16(v.z); o.w = f32_to_bf16(v.w);
  ((ushort4*)out)[i] = o;
}

// W_dec [DMODEL, DDICT] fp32 -> W_decT [DDICT, DMODEL] bf16
__global__ __launch_bounds__(256) void transpose_bf16_kernel(
    const float* __restrict__ in, unsigned short* __restrict__ out) {
  __shared__ float tile[32][33];
  int tx = threadIdx.x & 31;
  int ty = threadIdx.x >> 5;
  int c0 = blockIdx.x * 32;
  int r0 = blockIdx.y * 32;
#pragma unroll
  for (int i = 0; i < 32; i += 8)
    tile[ty + i][tx] = in[(size_t)(r0 + ty + i) * DDICT + c0 + tx];
  __syncthreads();
#pragma unroll
  for (int i = 0; i < 32; i += 8)
    out[(size_t)(c0 + ty + i) * DMODEL + r0 + tx] = f32_to_bf16(tile[tx][ty + i]);
}

// ---------------------------------------------------------------- encoder GEMM + threshold epilogue
// Round-1 proven loop (unchanged). NEW: XCD-affine, bn-grouped block remap.
// HW dispatches workgroup lin to XCD lin%8 (round-robin). Decode:
//   xcd = lin&7, k = lin>>3, bn_idx = xcd + 8*(k>>6), bm_idx = k&63
// -> each XCD processes ONE bn column (B panel 512 KB, L2-resident, reused by
// all 64 bm blocks) before moving to its next column. Previous bn-major grid
// streamed B from HBM 8x (FETCH 310 MB vs ~50 MB compulsory) and stalled every
// K-phase on ~900cy HBM-miss B loads with only 2 blocks/CU of TLP.
__global__ __launch_bounds__(256, 2) void gemm_enc_kernel(
    const unsigned short* __restrict__ A,
    const unsigned short* __restrict__ B,
    const float* __restrict__ bias,
    const float* __restrict__ tau,
    unsigned* __restrict__ cnt,
    int2* __restrict__ cand,
    float* __restrict__ out_z) {
  __shared__ __align__(16) unsigned short As[2][4][128][8];  // 16 KB dbuf
  __shared__ float taus[128];

  const int tid  = threadIdx.x;
  const int lane = tid & 63;
  const int wave = tid >> 6;
  const int l16  = lane & 15;
  const int quad = lane >> 4;

  // XCD-affine bijective decode (4096 blocks = 8 xcd * 8 cols * 64 rows)
  const int lin = blockIdx.x;
  const int xcd = lin & 7;
  const int k   = lin >> 3;                    // 0..511
  const int bn  = (xcd + ((k >> 6) << 3)) * 256;
  const int bm  = (k & 63) * 128;
  const int n0 = wave * 64;            // wave's col strip (block-local)

  if (tid < 128) taus[tid] = tau[bm + tid];

  // A staging: 512 chunks of 16B per K-step, 2 per thread, kc-major layout
  const int c0 = tid, c1 = tid + 256;
  const int kc0 = c0 >> 7, r0 = c0 & 127;
  const int kc1 = c1 >> 7, r1 = c1 & 127;
  const unsigned short* Ab = A + (size_t)bm * DMODEL;

  // B row pointers: frag j, lane reads 16B at [col][k0 + quad*8]
  const unsigned short* Bp[4];
#pragma unroll
  for (int j = 0; j < 4; ++j)
    Bp[j] = B + (size_t)(bn + n0 + j * 16 + l16) * DMODEL + quad * 8;

  f32x4 acc[8][4];
#pragma unroll
  for (int i = 0; i < 8; ++i)
#pragma unroll
    for (int j = 0; j < 4; ++j) acc[i][j] = f32x4{0.f, 0.f, 0.f, 0.f};

  bf16x8 b0[4], b1[4];

  // prologue: stage A(k=0) -> As[0], load B(k=0) -> b0
  GLD16(Ab + (size_t)r0 * DMODEL + kc0 * 8, &As[0][kc0][r0][0]);
  GLD16(Ab + (size_t)r1 * DMODEL + kc1 * 8, &As[0][kc1][r1][0]);
  __builtin_amdgcn_sched_barrier(0);
#pragma unroll
  for (int j = 0; j < 4; ++j) b0[j] = *(const bf16x8*)(Bp[j]);
  __builtin_amdgcn_sched_barrier(0);
  asm volatile("s_waitcnt vmcnt(4)" ::: "memory");  // drain A stores, keep B in flight
  __builtin_amdgcn_s_barrier();
  __builtin_amdgcn_sched_barrier(0);

#pragma unroll 1
  for (int k0 = 0; k0 < DMODEL; k0 += 64) {
    // ---- phase 0: compute [k0,k0+32) from As[0]/b0; prefetch k0+32 -> As[1]/b1
    GLD16(Ab + (size_t)r0 * DMODEL + (k0 + 32) + kc0 * 8, &As[1][kc0][r0][0]);
    GLD16(Ab + (size_t)r1 * DMODEL + (k0 + 32) + kc1 * 8, &As[1][kc1][r1][0]);
    __builtin_amdgcn_sched_barrier(0);   // pin: A stages are oldest vmem of phase
#pragma unroll
    for (int j = 0; j < 4; ++j) b1[j] = *(const bf16x8*)(Bp[j] + k0 + 32);
    __builtin_amdgcn_s_setprio(1);
#pragma unroll
    for (int i = 0; i < 8; ++i) {
      bf16x8 a = *(const bf16x8*)(&As[0][quad][i * 16 + l16][0]);
#pragma unroll
      for (int j = 0; j < 4; ++j)
        acc[i][j] = __builtin_amdgcn_mfma_f32_16x16x32_bf16(a, b0[j], acc[i][j], 0, 0, 0);
    }
    __builtin_amdgcn_s_setprio(0);
    __builtin_amdgcn_sched_barrier(0);
    asm volatile("s_waitcnt vmcnt(4)" ::: "memory");
    __builtin_amdgcn_s_barrier();
    __builtin_amdgcn_sched_barrier(0);

    // ---- phase 1: compute [k0+32,k0+64) from As[1]/b1; prefetch k0+64 -> As[0]/b0
    const bool more = (k0 + 64 < DMODEL);
    if (more) {
      GLD16(Ab + (size_t)r0 * DMODEL + (k0 + 64) + kc0 * 8, &As[0][kc0][r0][0]);
      GLD16(Ab + (size_t)r1 * DMODEL + (k0 + 64) + kc1 * 8, &As[0][kc1][r1][0]);
      __builtin_amdgcn_sched_barrier(0);
#pragma unroll
      for (int j = 0; j < 4; ++j) b0[j] = *(const bf16x8*)(Bp[j] + k0 + 64);
    }
    __builtin_amdgcn_s_setprio(1);
#pragma unroll
    for (int i = 0; i < 8; ++i) {
      bf16x8 a = *(const bf16x8*)(&As[1][quad][i * 16 + l16][0]);
#pragma unroll
      for (int j = 0; j < 4; ++j)
        acc[i][j] = __builtin_amdgcn_mfma_f32_16x16x32_bf16(a, b1[j], acc[i][j], 0, 0, 0);
    }
    __builtin_amdgcn_s_setprio(0);
    if (more) {
      __builtin_amdgcn_sched_barrier(0);
      asm volatile("s_waitcnt vmcnt(4)" ::: "memory");
      __builtin_amdgcn_s_barrier();
      __builtin_amdgcn_sched_barrier(0);
    }
  }

  // zero this block's 128x256 z tile (fire-and-forget; overlaps epilogue ALU;
  // cross-kernel ordering guarantees completion before select's scatter)
  {
    float* zt = out_z + (size_t)bm * DDICT + bn;
    const float4 z4 = make_float4(0.f, 0.f, 0.f, 0.f);
#pragma unroll
    for (int s = 0; s < 32; ++s) {
      int p = s * 256 + tid;          // 8192 float4 positions in 128x256 tile
      int rr = p >> 6, cc = p & 63;   // 64 float4 per row
      ((float4*)(zt + (size_t)rr * DDICT))[cc] = z4;
    }
  }

  // epilogue: m = i*16 + quad*4 + r (block-local), n = n0 + j*16 + l16
#pragma unroll
  for (int j = 0; j < 4; ++j) {
    int coll = n0 + j * 16 + l16;
    float bv = bias[bn + coll];
#pragma unroll
    for (int i = 0; i < 8; ++i)
#pragma unroll
      for (int r = 0; r < 4; ++r) {
        int rl = i * 16 + quad * 4 + r;
        float z = acc[i][j][r] + bv;
        if (__builtin_fabsf(z) >= taus[rl]) {
          int row = bm + rl;
          unsigned p = atomicAdd(&cnt[row], 1u);
          if (p < MAXC)
            cand[(size_t)row * MAXC + p] = make_int2(bn + coll, __float_as_int(z));
        }
      }
  }
}

// ---------------------------------------------------------------- select + refine + decode
// UNCHANGED from round 4 (deliberately): with gemm dropping, this kernel
// should claim the rocprof top-5 next run and expose its real counters.
__global__ __launch_bounds__(256) void select_kernel(
    const float* __restrict__ x,
    const float* __restrict__ Wenc,
    const float* __restrict__ benc,
    const unsigned short* __restrict__ wdTb,
    const float* __restrict__ bdec,
    const unsigned* __restrict__ cnt,
    const int2* __restrict__ cand,
    float* __restrict__ out_recon,
    float* __restrict__ out_z) {
  const int lane = threadIdx.x & 63;
  const int wave = threadIdx.x >> 6;
  const int row  = blockIdx.x * 4 + wave;

  // ---- x row into registers as float4 (lane covers dims [lane*4 + t*256 ..])
  float4 x4[4];
  const float4* xrow4 = (const float4*)(x + (size_t)row * DMODEL);
#pragma unroll
  for (int t = 0; t < 4; ++t) x4[t] = xrow4[lane + t * 64];

  // ---- candidates (4 slots per lane)
  int n = (int)cnt[row];
  if (n > MAXC) n = MAXC;
  int ccol[4]; float cval[4]; unsigned ckey[4]; bool act[4];
#pragma unroll
  for (int c = 0; c < 4; ++c) {
    const int idx = c * 64 + lane;
    act[c] = idx < n;
    ccol[c] = 0x7FFFFFFF; cval[c] = 0.f; ckey[c] = 0u;
    if (act[c]) {
      int2 cv = cand[(size_t)row * MAXC + idx];
      ccol[c] = cv.x;
      cval[c] = __int_as_float(cv.y);
      ckey[c] = (unsigned)cv.y & 0x7FFFFFFFu;
    }
  }

  // ---- bisect 32nd-largest approx |z| (wave-local, no barriers)
  const int nw = n < TOPK ? n : TOPK;
  unsigned lo = 0u, hi = 0x7F800000u;
  for (int it = 0; it < 28; ++it) {
    const unsigned mid = (lo + hi) >> 1;
    int tot = 0;
#pragma unroll
    for (int c = 0; c < 4; ++c)
      tot += __popcll(__ballot(act[c] && ckey[c] >= mid));
    if (tot >= nw) lo = mid; else hi = mid;
  }
  const float t32 = __uint_as_float(lo);

  // ---- membership flags
  bool fin[4], amb[4];
#pragma unroll
  for (int c = 0; c < 4; ++c) {
    const float ab = __uint_as_float(ckey[c]);
    fin[c] = act[c] && (ab > t32 + DELTA);
    amb[c] = act[c] && !fin[c] && (ab >= t32 - DELTA);
  }
  int nI = 0, nA = 0;
#pragma unroll
  for (int c = 0; c < 4; ++c) {
    nI += __popcll(__ballot(fin[c]));
    nA += __popcll(__ballot(amb[c]));
  }

  // ---- exact fp64 dots for every ambiguous candidate (whole wave each)
  double dval[4] = {0.0, 0.0, 0.0, 0.0};
#pragma unroll
  for (int c = 0; c < 4; ++c) {
    unsigned long long bits = __ballot(amb[c]);
    while (bits) {
      const int src = __ffsll(bits) - 1;
      bits &= bits - 1;
      const int j = __shfl(ccol[c], src);
      const float4* wr4 = (const float4*)(Wenc + (size_t)j * DMODEL);
      double s = 0.0;
#pragma unroll
      for (int t = 0; t < 4; ++t) {
        const float4 wv = wr4[lane + t * 64];
        s += (double)x4[t].x * (double)wv.x + (double)x4[t].y * (double)wv.y +
             (double)x4[t].z * (double)wv.z + (double)x4[t].w * (double)wv.w;
      }
#pragma unroll
      for (int off = 32; off; off >>= 1) s += __shfl_down(s, off);
      const double dv = __shfl(s, 0) + (double)benc[j];
      if (lane == src) {
#pragma unroll
        for (int cc = 0; cc < 4; ++cc)
          if (cc == c) dval[cc] = dv;
      }
    }
  }

  // ---- pick top-`need` ambiguous by exact |val| (tie: lower dict index)
  int need = TOPK - nI;
  if (need < 0) need = 0;
  if (need > nA) need = nA;
  for (int pick = 0; pick < need; ++pick) {
    double ba = -1.0; int bcol = 0x7FFFFFFF; int bslot = -1;
#pragma unroll
    for (int c = 0; c < 4; ++c)
      if (amb[c]) {
        const double va = fabs(dval[c]);
        if (va > ba || (va == ba && ccol[c] < bcol)) {
          ba = va; bcol = ccol[c]; bslot = c;
        }
      }
    int bl = lane;
#pragma unroll
    for (int off = 32; off; off >>= 1) {
      const double oa = __shfl_down(ba, off);
      const int    oc = __shfl_down(bcol, off);
      const int    ol = __shfl_down(bl, off);
      if (oa > ba || (oa == ba && oc < bcol)) { ba = oa; bcol = oc; bl = ol; }
    }
    bl = __shfl(bl, 0);
    if (lane == bl) {
      // winner lane: its local (ba,bslot) is the global winner; static-index update
#pragma unroll
      for (int c = 0; c < 4; ++c)
        if (c == bslot) {
          amb[c] = false;
          fin[c] = true;
          cval[c] = (float)dval[c];
        }
    }
  }

  // ---- fused sparse decode from bf16 WdT; lane owns dims [8*lane..8*lane+7]
  //      and [512+8*lane..512+8*lane+7]
  float ax[16];
  {
    const float4* b4 = (const float4*)bdec;
    float4 t0 = b4[2 * lane],       t1 = b4[2 * lane + 1];
    float4 t2 = b4[128 + 2 * lane], t3 = b4[129 + 2 * lane];
    ax[0] = t0.x; ax[1] = t0.y; ax[2]  = t0.z; ax[3]  = t0.w;
    ax[4] = t1.x; ax[5] = t1.y; ax[6]  = t1.z; ax[7]  = t1.w;
    ax[8] = t2.x; ax[9] = t2.y; ax[10] = t2.z; ax[11] = t2.w;
    ax[12] = t3.x; ax[13] = t3.y; ax[14] = t3.z; ax[15] = t3.w;
  }
#pragma unroll
  for (int c = 0; c < 4; ++c) {
    unsigned long long bits = __ballot(fin[c]);
    while (bits) {
      const int src = __ffsll(bits) - 1;
      bits &= bits - 1;
      const int   j  = __shfl(ccol[c], src);
      const float zv = __shfl(cval[c], src);
      const unsigned short* wrow = wdTb + (size_t)j * DMODEL;
      bf16x8 w0 = ((const bf16x8*)wrow)[lane];
      bf16x8 w1 = ((const bf16x8*)wrow)[lane + 64];
#pragma unroll
      for (int k = 0; k < 8; ++k) {
        ax[k]     = fmaf(zv, bf2f((unsigned short)w0[k]), ax[k]);
        ax[8 + k] = fmaf(zv, bf2f((unsigned short)w1[k]), ax[8 + k]);
      }
    }
  }
  {
    float4* r4 = (float4*)(out_recon + (size_t)row * DMODEL);
    r4[2 * lane]       = make_float4(ax[0], ax[1], ax[2], ax[3]);
    r4[2 * lane + 1]   = make_float4(ax[4], ax[5], ax[6], ax[7]);
    r4[128 + 2 * lane] = make_float4(ax[8], ax[9], ax[10], ax[11]);
    r4[129 + 2 * lane] = make_float4(ax[12], ax[13], ax[14], ax[15]);
  }

  // ---- z scatter (tile pre-zeroed by gemm; cross-kernel order guarantees it)
  float* zrow = out_z + (size_t)row * DDICT;
#pragma unroll
  for (int c = 0; c < 4; ++c)
    if (fin[c]) zrow[ccol[c]] = cval[c];
}

// ---------------------------------------------------------------- launch
extern "C" void kernel_launch(void* const* d_in, const int* in_sizes, int n_in,
                              void* d_out, int out_size, void* d_ws, size_t ws_size,
                              hipStream_t stream) {
  const float* x    = (const float*)d_in[0];
  const float* Wenc = (const float*)d_in[1];
  const float* benc = (const float*)d_in[2];
  const float* Wdec = (const float*)d_in[3];
  const float* bdec = (const float*)d_in[4];

  float* out_recon = (float*)d_out;
  float* out_z     = (float*)d_out + (size_t)M_TOK * DMODEL;

  // ws carve: xbf 16MB | wbf 33.5MB | wdTb 33.5MB | cand 16.8MB | tau 32KB | cnt 32KB
  char* w = (char*)d_ws;
  unsigned short* xbf  = (unsigned short*)w;                w += (size_t)M_TOK * DMODEL * 2;
  unsigned short* wbf  = (unsigned short*)w;                w += (size_t)DDICT * DMODEL * 2;
  unsigned short* wdTb = (unsigned short*)w;                w += (size_t)DDICT * DMODEL * 2;
  int2*           cand = (int2*)w;                          w += (size_t)M_TOK * MAXC * 8;
  float*          tau  = (float*)w;                         w += (size_t)M_TOK * 4;
  unsigned*       cnt  = (unsigned*)w;

  hipMemsetAsync(cnt, 0, (size_t)M_TOK * 4, stream);
  // out_z zero-fill is fused into gemm_enc_kernel's epilogue.

  cast_x_norm_kernel<<<M_TOK, 256, 0, stream>>>(x, xbf, tau);
  {
    int n4 = DDICT * DMODEL / 4;
    cast_bf16_kernel<<<(n4 + 255) / 256, 256, 0, stream>>>(Wenc, wbf, n4);
  }
  {
    dim3 g(DDICT / 32, DMODEL / 32);
    transpose_bf16_kernel<<<g, 256, 0, stream>>>(Wdec, wdTb);
  }
  {
    // 4096 blocks, XCD-affine bn-grouped decode in-kernel
    gemm_enc_kernel<<<(DDICT / 256) * (M_TOK / 128), 256, 0, stream>>>(
        xbf, wbf, benc, tau, cnt, cand, out_z);
  }
  select_kernel<<<M_TOK / 4, 256, 0, stream>>>(x, Wenc, benc, wdTb, bdec, cnt, cand,
                                               out_recon, out_z);
}

// Round 6
// 1305.685 us; speedup vs baseline: 1.1628x; 1.0279x over previous
//
#include <hip/hip_runtime.h>
#include <stdint.h>

#define M_TOK   8192
#define DMODEL  1024
#define DDICT   16384
#define TOPK    32
#define MAXC    256     // per-row candidate capacity (E[cnt]~98, P(>256)~0)
#define DELTA   0.03f   // certainty margin vs bf16-GEMM error (sigma ~1e-3)

typedef __attribute__((ext_vector_type(8))) short bf16x8;
typedef __attribute__((ext_vector_type(4))) float f32x4;

// ---------------------------------------------------------------- helpers
__device__ __forceinline__ unsigned short f32_to_bf16(float f) {
  unsigned u = __float_as_uint(f);
  unsigned r = 0x7FFFu + ((u >> 16) & 1u);   // round-to-nearest-even
  return (unsigned short)((u + r) >> 16);
}

__device__ __forceinline__ float bf2f(unsigned short h) {
  return __uint_as_float(((unsigned)h) << 16);
}

#define GLD16(g, l)                                                        \
  __builtin_amdgcn_global_load_lds(                                        \
      (const __attribute__((address_space(1))) void*)(g),                  \
      (__attribute__((address_space(3))) void*)(l), 16, 0, 0)

// ---------------------------------------------------------------- x cast + row norm -> tau
__global__ __launch_bounds__(256) void cast_x_norm_kernel(
    const float* __restrict__ x, unsigned short* __restrict__ xbf,
    float* __restrict__ tau) {
  const int row = blockIdx.x, tid = threadIdx.x;
  const int lane = tid & 63, wave = tid >> 6;
  __shared__ float red[4];
  float4 v = ((const float4*)(x + (size_t)row * DMODEL))[tid];
  ushort4 o;
  o.x = f32_to_bf16(v.x); o.y = f32_to_bf16(v.y);
  o.z = f32_to_bf16(v.z); o.w = f32_to_bf16(v.w);
  ((ushort4*)(xbf + (size_t)row * DMODEL))[tid] = o;
  float ss = v.x * v.x + v.y * v.y + v.z * v.z + v.w * v.w;
#pragma unroll
  for (int off = 32; off; off >>= 1) ss += __shfl_down(ss, off);
  if (lane == 0) red[wave] = ss;
  __syncthreads();
  if (tid == 0) tau[row] = 0.055f * sqrtf(red[0] + red[1] + red[2] + red[3]);
}

// ---------------------------------------------------------------- Wenc cast
__global__ __launch_bounds__(256) void cast_bf16_kernel(
    const float* __restrict__ in, unsigned short* __restrict__ out, int n4) {
  int i = blockIdx.x * 256 + threadIdx.x;
  if (i >= n4) return;
  float4 v = ((const float4*)in)[i];
  ushort4 o;
  o.x = f32_to_bf16(v.x); o.y = f32_to_bf16(v.y);
  o.z = f32_to_bf16(v.z); o.w = f32_to_bf16(v.w);
  ((ushort4*)out)[i] = o;
}

// W_dec [DMODEL, DDICT] fp32 -> W_decT [DDICT, DMODEL] bf16
__global__ __launch_bounds__(256) void transpose_bf16_kernel(
    const float* __restrict__ in, unsigned short* __restrict__ out) {
  __shared__ float tile[32][33];
  int tx = threadIdx.x & 31;
  int ty = threadIdx.x >> 5;
  int c0 = blockIdx.x * 32;
  int r0 = blockIdx.y * 32;
#pragma unroll
  for (int i = 0; i < 32; i += 8)
    tile[ty + i][tx] = in[(size_t)(r0 + ty + i) * DDICT + c0 + tx];
  __syncthreads();
#pragma unroll
  for (int i = 0; i < 32; i += 8)
    out[(size_t)(c0 + ty + i) * DMODEL + r0 + tx] = f32_to_bf16(tile[tx][ty + i]);
}

// ---------------------------------------------------------------- encoder GEMM + threshold epilogue
// 256x256 tile, 512 threads (8 waves 2Mx4N, wave tile 128x64), BK=32,
// TRIPLE-buffered LDS (96 KB, 1 block/CU -- m201 regime), both operands
// GLD16-staged, prefetch distance 2, counted vmcnt(4) per K-tile boundary
// (never 0 in the main loop), raw s_barrier, setprio around MFMA clusters.
//
// Line-request engineering (the r0-r5 ~6000cy/phase stall was VMEM request
// serialization): staging lanes map 4-per-row along K so 4 lanes cover one
// full 64B line -> 16 line-requests per GLD16 (vs 64 with row-per-lane).
// Bank-conflict-free fragment reads via both-sides XOR swizzle (rule #21):
// LDS slot (r,kc) holds global chunk kc^(r&3) (pre-swizzled SOURCE, linear
// GLD16 dest); reads use slot quad^(l16&3) -- per-thread constants, 2-way
// bank aliasing (free), line coalescing preserved (permutation within line).
__global__ __launch_bounds__(512, 2) void gemm_enc_kernel(
    const unsigned short* __restrict__ A,
    const unsigned short* __restrict__ B,
    const float* __restrict__ bias,
    const float* __restrict__ tau,
    unsigned* __restrict__ cnt,
    int2* __restrict__ cand,
    float* __restrict__ out_z) {
  __shared__ __align__(16) unsigned short As[3][256][32];  // 48 KB
  __shared__ __align__(16) unsigned short Bs[3][256][32];  // 48 KB
  __shared__ float taus[256];

  const int tid  = threadIdx.x;
  const int lane = tid & 63;
  const int wave = tid >> 6;
  const int l16  = lane & 15;
  const int quad = lane >> 4;
  const int wm   = (wave >> 2) * 128;   // wave M-offset (2 groups)
  const int wn   = (wave & 3) * 64;     // wave N-offset (4 groups)

  // XCD-affine bijective decode: 2048 blocks = 8 xcd * 8 bn-groups * 32 bm
  const int lin = blockIdx.x;
  const int xcd = lin & 7;
  const int k   = lin >> 3;                    // 0..255
  const int bn  = (xcd + ((k >> 5) << 3)) * 256;
  const int bm  = (k & 31) * 256;

  if (tid < 256) taus[tid] = tau[bm + tid];

  // staging: per K-tile each operand = 256 rows x 32 cols x 2B = 1024 chunks
  // of 16B; thread handles chunks g = tid and g = 512+tid with g=(row<<2)|kc.
  const int rq  = tid >> 2;          // row for q=0 (q=1 adds 128)
  const int kcs = tid & 3;           // LDS slot chunk index
  const int colOff = (kcs ^ (rq & 3)) * 8;  // pre-swizzled SOURCE column
  const unsigned short* Ab = A + (size_t)bm * DMODEL;
  const unsigned short* Bb = B + (size_t)bn * DMODEL;

  // fragment read slot (both-sides swizzle): per-thread constant
  const int rdk = (quad ^ (l16 & 3)) * 8;

  f32x4 acc[8][4];
#pragma unroll
  for (int i = 0; i < 8; ++i)
#pragma unroll
    for (int j = 0; j < 4; ++j) acc[i][j] = f32x4{0.f, 0.f, 0.f, 0.f};

#define STAGE(sb, kt)                                                         \
  do {                                                                        \
    const int kk = (kt) * 32 + colOff;                                        \
    GLD16(Ab + (size_t)rq * DMODEL + kk,          &As[sb][rq][kcs * 8]);      \
    GLD16(Ab + (size_t)(rq + 128) * DMODEL + kk,  &As[sb][rq + 128][kcs * 8]);\
    GLD16(Bb + (size_t)rq * DMODEL + kk,          &Bs[sb][rq][kcs * 8]);      \
    GLD16(Bb + (size_t)(rq + 128) * DMODEL + kk,  &Bs[sb][rq + 128][kcs * 8]);\
  } while (0)

#define COMPUTE(cb)                                                           \
  do {                                                                        \
    bf16x8 bf[4], af[4];                                                      \
    _Pragma("unroll")                                                         \
    for (int j = 0; j < 4; ++j)                                               \
      bf[j] = *(const bf16x8*)(&Bs[cb][wn + j * 16 + l16][rdk]);              \
    _Pragma("unroll")                                                         \
    for (int i = 0; i < 4; ++i)                                               \
      af[i] = *(const bf16x8*)(&As[cb][wm + i * 16 + l16][rdk]);              \
    __builtin_amdgcn_s_setprio(1);                                            \
    _Pragma("unroll")                                                         \
    for (int i = 0; i < 4; ++i)                                               \
      _Pragma("unroll")                                                       \
      for (int j = 0; j < 4; ++j)                                             \
        acc[i][j] = __builtin_amdgcn_mfma_f32_16x16x32_bf16(af[i], bf[j],     \
                                                            acc[i][j], 0, 0, 0); \
    __builtin_amdgcn_s_setprio(0);                                            \
    __builtin_amdgcn_sched_barrier(0);                                        \
    _Pragma("unroll")                                                         \
    for (int i = 0; i < 4; ++i)                                               \
      af[i] = *(const bf16x8*)(&As[cb][wm + 64 + i * 16 + l16][rdk]);         \
    __builtin_amdgcn_s_setprio(1);                                            \
    _Pragma("unroll")                                                         \
    for (int i = 0; i < 4; ++i)                                               \
      _Pragma("unroll")                                                       \
      for (int j = 0; j < 4; ++j)                                             \
        acc[4 + i][j] = __builtin_amdgcn_mfma_f32_16x16x32_bf16(af[i], bf[j], \
                                                            acc[4 + i][j], 0, 0, 0); \
    __builtin_amdgcn_s_setprio(0);                                            \
  } while (0)

  // prologue: stage K-tiles 0,1 -> bufs 0,1; wait tile-0's 4 loads, barrier
  STAGE(0, 0);
  STAGE(1, 1);
  __builtin_amdgcn_sched_barrier(0);
  asm volatile("s_waitcnt vmcnt(4)" ::: "memory");
  __builtin_amdgcn_s_barrier();
  __builtin_amdgcn_sched_barrier(0);

  int cb = 0, sb = 2;
#pragma unroll 1
  for (int kt = 0; kt < 32; ++kt) {
    if (kt < 30) {
      STAGE(sb, kt + 2);               // distance-2 prefetch into buf (kt+2)%3
      __builtin_amdgcn_sched_barrier(0);
    }
    COMPUTE(cb);
    if (kt < 31) {
      __builtin_amdgcn_sched_barrier(0);
      // outstanding: kt+1's 4 loads (oldest) + kt+2's 4 -> vmcnt(4) readies
      // kt+1 while kt+2 stays in flight; final boundary drains all.
      if (kt == 30) asm volatile("s_waitcnt vmcnt(0)" ::: "memory");
      else          asm volatile("s_waitcnt vmcnt(4)" ::: "memory");
      __builtin_amdgcn_s_barrier();
      __builtin_amdgcn_sched_barrier(0);
    }
    cb = (cb == 2) ? 0 : cb + 1;
    sb = (sb == 2) ? 0 : sb + 1;
  }

#undef COMPUTE
#undef STAGE

  // zero this block's 256x256 z tile (fire-and-forget; overlaps epilogue ALU;
  // cross-kernel ordering guarantees completion before select's scatter)
  {
    float* zt = out_z + (size_t)bm * DDICT + bn;
    const float4 z4 = make_float4(0.f, 0.f, 0.f, 0.f);
#pragma unroll
    for (int s = 0; s < 32; ++s) {
      int p = s * 512 + tid;          // 16384 float4 positions in 256x256 tile
      int rr = p >> 6, cc = p & 63;   // 64 float4 per row
      ((float4*)(zt + (size_t)rr * DDICT))[cc] = z4;
    }
  }

  // threshold epilogue: m = bm + wm + i*16 + quad*4 + r, n = bn + wn + j*16 + l16
#pragma unroll
  for (int j = 0; j < 4; ++j) {
    int coll = wn + j * 16 + l16;
    float bv = bias[bn + coll];
#pragma unroll
    for (int i = 0; i < 8; ++i)
#pragma unroll
      for (int r = 0; r < 4; ++r) {
        int rl = wm + i * 16 + quad * 4 + r;
        float z = acc[i][j][r] + bv;
        if (__builtin_fabsf(z) >= taus[rl]) {
          int row = bm + rl;
          unsigned p = atomicAdd(&cnt[row], 1u);
          if (p < MAXC)
            cand[(size_t)row * MAXC + p] = make_int2(bn + coll, __float_as_int(z));
        }
      }
  }
}

// ---------------------------------------------------------------- select + refine + decode
// UNCHANGED (wave-per-row, barrier-free). With gemm dropping it should claim
// the rocprof top-5 next run and expose its real counters.
__global__ __launch_bounds__(256) void select_kernel(
    const float* __restrict__ x,
    const float* __restrict__ Wenc,
    const float* __restrict__ benc,
    const unsigned short* __restrict__ wdTb,
    const float* __restrict__ bdec,
    const unsigned* __restrict__ cnt,
    const int2* __restrict__ cand,
    float* __restrict__ out_recon,
    float* __restrict__ out_z) {
  const int lane = threadIdx.x & 63;
  const int wave = threadIdx.x >> 6;
  const int row  = blockIdx.x * 4 + wave;

  // ---- x row into registers as float4 (lane covers dims [lane*4 + t*256 ..])
  float4 x4[4];
  const float4* xrow4 = (const float4*)(x + (size_t)row * DMODEL);
#pragma unroll
  for (int t = 0; t < 4; ++t) x4[t] = xrow4[lane + t * 64];

  // ---- candidates (4 slots per lane)
  int n = (int)cnt[row];
  if (n > MAXC) n = MAXC;
  int ccol[4]; float cval[4]; unsigned ckey[4]; bool act[4];
#pragma unroll
  for (int c = 0; c < 4; ++c) {
    const int idx = c * 64 + lane;
    act[c] = idx < n;
    ccol[c] = 0x7FFFFFFF; cval[c] = 0.f; ckey[c] = 0u;
    if (act[c]) {
      int2 cv = cand[(size_t)row * MAXC + idx];
      ccol[c] = cv.x;
      cval[c] = __int_as_float(cv.y);
      ckey[c] = (unsigned)cv.y & 0x7FFFFFFFu;
    }
  }

  // ---- bisect 32nd-largest approx |z| (wave-local, no barriers)
  const int nw = n < TOPK ? n : TOPK;
  unsigned lo = 0u, hi = 0x7F800000u;
  for (int it = 0; it < 28; ++it) {
    const unsigned mid = (lo + hi) >> 1;
    int tot = 0;
#pragma unroll
    for (int c = 0; c < 4; ++c)
      tot += __popcll(__ballot(act[c] && ckey[c] >= mid));
    if (tot >= nw) lo = mid; else hi = mid;
  }
  const float t32 = __uint_as_float(lo);

  // ---- membership flags
  bool fin[4], amb[4];
#pragma unroll
  for (int c = 0; c < 4; ++c) {
    const float ab = __uint_as_float(ckey[c]);
    fin[c] = act[c] && (ab > t32 + DELTA);
    amb[c] = act[c] && !fin[c] && (ab >= t32 - DELTA);
  }
  int nI = 0, nA = 0;
#pragma unroll
  for (int c = 0; c < 4; ++c) {
    nI += __popcll(__ballot(fin[c]));
    nA += __popcll(__ballot(amb[c]));
  }

  // ---- exact fp64 dots for every ambiguous candidate (whole wave each)
  double dval[4] = {0.0, 0.0, 0.0, 0.0};
#pragma unroll
  for (int c = 0; c < 4; ++c) {
    unsigned long long bits = __ballot(amb[c]);
    while (bits) {
      const int src = __ffsll(bits) - 1;
      bits &= bits - 1;
      const int j = __shfl(ccol[c], src);
      const float4* wr4 = (const float4*)(Wenc + (size_t)j * DMODEL);
      double s = 0.0;
#pragma unroll
      for (int t = 0; t < 4; ++t) {
        const float4 wv = wr4[lane + t * 64];
        s += (double)x4[t].x * (double)wv.x + (double)x4[t].y * (double)wv.y +
             (double)x4[t].z * (double)wv.z + (double)x4[t].w * (double)wv.w;
      }
#pragma unroll
      for (int off = 32; off; off >>= 1) s += __shfl_down(s, off);
      const double dv = __shfl(s, 0) + (double)benc[j];
      if (lane == src) {
#pragma unroll
        for (int cc = 0; cc < 4; ++cc)
          if (cc == c) dval[cc] = dv;
      }
    }
  }

  // ---- pick top-`need` ambiguous by exact |val| (tie: lower dict index)
  int need = TOPK - nI;
  if (need < 0) need = 0;
  if (need > nA) need = nA;
  for (int pick = 0; pick < need; ++pick) {
    double ba = -1.0; int bcol = 0x7FFFFFFF; int bslot = -1;
#pragma unroll
    for (int c = 0; c < 4; ++c)
      if (amb[c]) {
        const double va = fabs(dval[c]);
        if (va > ba || (va == ba && ccol[c] < bcol)) {
          ba = va; bcol = ccol[c]; bslot = c;
        }
      }
    int bl = lane;
#pragma unroll
    for (int off = 32; off; off >>= 1) {
      const double oa = __shfl_down(ba, off);
      const int    oc = __shfl_down(bcol, off);
      const int    ol = __shfl_down(bl, off);
      if (oa > ba || (oa == ba && oc < bcol)) { ba = oa; bcol = oc; bl = ol; }
    }
    bl = __shfl(bl, 0);
    if (lane == bl) {
      // winner lane: its local (ba,bslot) is the global winner; static-index update
#pragma unroll
      for (int c = 0; c < 4; ++c)
        if (c == bslot) {
          amb[c] = false;
          fin[c] = true;
          cval[c] = (float)dval[c];
        }
    }
  }

  // ---- fused sparse decode from bf16 WdT; lane owns dims [8*lane..8*lane+7]
  //      and [512+8*lane..512+8*lane+7]
  float ax[16];
  {
    const float4* b4 = (const float4*)bdec;
    float4 t0 = b4[2 * lane],       t1 = b4[2 * lane + 1];
    float4 t2 = b4[128 + 2 * lane], t3 = b4[129 + 2 * lane];
    ax[0] = t0.x; ax[1] = t0.y; ax[2]  = t0.z; ax[3]  = t0.w;
    ax[4] = t1.x; ax[5] = t1.y; ax[6]  = t1.z; ax[7]  = t1.w;
    ax[8] = t2.x; ax[9] = t2.y; ax[10] = t2.z; ax[11] = t2.w;
    ax[12] = t3.x; ax[13] = t3.y; ax[14] = t3.z; ax[15] = t3.w;
  }
#pragma unroll
  for (int c = 0; c < 4; ++c) {
    unsigned long long bits = __ballot(fin[c]);
    while (bits) {
      const int src = __ffsll(bits) - 1;
      bits &= bits - 1;
      const int   j  = __shfl(ccol[c], src);
      const float zv = __shfl(cval[c], src);
      const unsigned short* wrow = wdTb + (size_t)j * DMODEL;
      bf16x8 w0 = ((const bf16x8*)wrow)[lane];
      bf16x8 w1 = ((const bf16x8*)wrow)[lane + 64];
#pragma unroll
      for (int kq = 0; kq < 8; ++kq) {
        ax[kq]     = fmaf(zv, bf2f((unsigned short)w0[kq]), ax[kq]);
        ax[8 + kq] = fmaf(zv, bf2f((unsigned short)w1[kq]), ax[8 + kq]);
      }
    }
  }
  {
    float4* r4 = (float4*)(out_recon + (size_t)row * DMODEL);
    r4[2 * lane]       = make_float4(ax[0], ax[1], ax[2], ax[3]);
    r4[2 * lane + 1]   = make_float4(ax[4], ax[5], ax[6], ax[7]);
    r4[128 + 2 * lane] = make_float4(ax[8], ax[9], ax[10], ax[11]);
    r4[129 + 2 * lane] = make_float4(ax[12], ax[13], ax[14], ax[15]);
  }

  // ---- z scatter (tile pre-zeroed by gemm; cross-kernel order guarantees it)
  float* zrow = out_z + (size_t)row * DDICT;
#pragma unroll
  for (int c = 0; c < 4; ++c)
    if (fin[c]) zrow[ccol[c]] = cval[c];
}

// ---------------------------------------------------------------- launch
extern "C" void kernel_launch(void* const* d_in, const int* in_sizes, int n_in,
                              void* d_out, int out_size, void* d_ws, size_t ws_size,
                              hipStream_t stream) {
  const float* x    = (const float*)d_in[0];
  const float* Wenc = (const float*)d_in[1];
  const float* benc = (const float*)d_in[2];
  const float* Wdec = (const float*)d_in[3];
  const float* bdec = (const float*)d_in[4];

  float* out_recon = (float*)d_out;
  float* out_z     = (float*)d_out + (size_t)M_TOK * DMODEL;

  // ws carve: xbf 16MB | wbf 33.5MB | wdTb 33.5MB | cand 16.8MB | tau 32KB | cnt 32KB
  char* w = (char*)d_ws;
  unsigned short* xbf  = (unsigned short*)w;                w += (size_t)M_TOK * DMODEL * 2;
  unsigned short* wbf  = (unsigned short*)w;                w += (size_t)DDICT * DMODEL * 2;
  unsigned short* wdTb = (unsigned short*)w;                w += (size_t)DDICT * DMODEL * 2;
  int2*           cand = (int2*)w;                          w += (size_t)M_TOK * MAXC * 8;
  float*          tau  = (float*)w;                         w += (size_t)M_TOK * 4;
  unsigned*       cnt  = (unsigned*)w;

  hipMemsetAsync(cnt, 0, (size_t)M_TOK * 4, stream);
  // out_z zero-fill is fused into gemm_enc_kernel's epilogue.

  cast_x_norm_kernel<<<M_TOK, 256, 0, stream>>>(x, xbf, tau);
  {
    int n4 = DDICT * DMODEL / 4;
    cast_bf16_kernel<<<(n4 + 255) / 256, 256, 0, stream>>>(Wenc, wbf, n4);
  }
  {
    dim3 g(DDICT / 32, DMODEL / 32);
    transpose_bf16_kernel<<<g, 256, 0, stream>>>(Wdec, wdTb);
  }
  {
    // 2048 blocks = (DDICT/256) * (M_TOK/256); XCD-affine decode in-kernel
    gemm_enc_kernel<<<(DDICT / 256) * (M_TOK / 256), 512, 0, stream>>>(
        xbf, wbf, benc, tau, cnt, cand, out_z);
  }
  select_kernel<<<M_TOK / 4, 256, 0, stream>>>(x, Wenc, benc, wdTb, bdec, cnt, cand,
                                               out_recon, out_z);
}